// Round 1
// baseline (1177.371 us; speedup 1.0000x reference)
//
#include <hip/hip_runtime.h>
#include <hip/hip_bf16.h>

typedef __attribute__((ext_vector_type(8))) short short8;
typedef __attribute__((ext_vector_type(4))) float f32x4;

#define B_SZ 4
#define T_SEQ 2048
#define C_DIM 2048
#define NH 16
#define NKV 4
#define HD 128

__device__ __forceinline__ unsigned short f2bf(float f) {
  union { __hip_bfloat16 h; unsigned short u; } v;
  v.h = __float2bfloat16(f);
  return v.u;
}
__device__ __forceinline__ float bf2f(unsigned short u) {
  union { unsigned short u; __hip_bfloat16 h; } v;
  v.u = u;
  return __bfloat162float(v.h);
}

__device__ __forceinline__ void gload_lds16(const unsigned short* g, unsigned short* l) {
  __builtin_amdgcn_global_load_lds(
      (const __attribute__((address_space(1))) unsigned int*)g,
      (__attribute__((address_space(3))) unsigned int*)l, 16, 0, 0);
}

// ---------------- cast x (fp32 -> bf16), vectorized ----------------
__global__ void cast_x(const float* __restrict__ x, unsigned short* __restrict__ xb, int n4) {
  int i = blockIdx.x * blockDim.x + threadIdx.x;
  if (i < n4) {
    float4 f = ((const float4*)x)[i];
    ushort4 u = make_ushort4(f2bf(f.x), f2bf(f.y), f2bf(f.z), f2bf(f.w));
    ((ushort4*)xb)[i] = u;
  }
}

// ---------------- weight transpose+cast: W (K x N) fp32 -> Wt (N x K) bf16 ----------------
__global__ void wtrans(const float* __restrict__ W, unsigned short* __restrict__ Wt, int K, int N) {
  __shared__ float tile[32][33];
  int k0 = blockIdx.x * 32, n0 = blockIdx.y * 32;
  int tx = threadIdx.x, ty = threadIdx.y;
#pragma unroll
  for (int i = 0; i < 4; i++)
    tile[ty + i * 8][tx] = W[(size_t)(k0 + ty + i * 8) * N + n0 + tx];
  __syncthreads();
#pragma unroll
  for (int i = 0; i < 4; i++)
    Wt[(size_t)(n0 + ty + i * 8) * K + k0 + tx] = f2bf(tile[tx][ty + i * 8]);
}

// ---------------- V transpose: (B,T,KVH,D) bf16 -> (B,KVH,D,T) bf16 ----------------
__global__ void vtrans(const unsigned short* __restrict__ v, unsigned short* __restrict__ Vt) {
  __shared__ unsigned short tile[32][34];
  int t0 = blockIdx.x * 32, d0 = blockIdx.y * 32;
  int b = blockIdx.z >> 2, kvh = blockIdx.z & 3;
  int tx = threadIdx.x, ty = threadIdx.y;
#pragma unroll
  for (int i = 0; i < 4; i++)
    tile[ty + i * 8][tx] = v[((size_t)(b * T_SEQ + t0 + ty + i * 8) * NKV + kvh) * HD + d0 + tx];
  __syncthreads();
#pragma unroll
  for (int i = 0; i < 4; i++)
    Vt[((size_t)(b * NKV + kvh) * HD + d0 + ty + i * 8) * T_SEQ + t0 + tx] = tile[tx][ty + i * 8];
}

// ---------------- GEMM: C[M,N] = A[M,K] * Bt[N,K]^T, bf16 in, OutT out ----------------
// 128x128 tile, BK=32, 4 waves (2x2), 16x16x32 MFMA, global_load_lds staging (m97 structure)
template <typename OutT>
__global__ __launch_bounds__(256, 2) void gemm_bt(const unsigned short* __restrict__ A,
                                                  const unsigned short* __restrict__ Bt,
                                                  OutT* __restrict__ Cc, int M, int N, int K) {
  __shared__ alignas(16) unsigned short lA[128 * 32];
  __shared__ alignas(16) unsigned short lB[128 * 32];
  const int tid = threadIdx.x, lane = tid & 63, wid = tid >> 6;
  const int wr = wid >> 1, wc = wid & 1;
  const size_t row0 = (size_t)blockIdx.x * 128, col0 = (size_t)blockIdx.y * 128;
  const int lr = lane >> 2, lc = (lane & 3) * 8;
  f32x4 zero = {0.f, 0.f, 0.f, 0.f};
  f32x4 acc[4][4];
#pragma unroll
  for (int m = 0; m < 4; m++)
#pragma unroll
    for (int n = 0; n < 4; n++) acc[m][n] = zero;

  for (int k0 = 0; k0 < K; k0 += 32) {
#pragma unroll
    for (int j = 0; j < 2; ++j) {
      int chunk = wid * 2 + j;  // 0..7, covers 16 tile-rows each
      gload_lds16(A + (row0 + chunk * 16 + lr) * K + k0 + lc, lA + chunk * 512);
      gload_lds16(Bt + (col0 + chunk * 16 + lr) * K + k0 + lc, lB + chunk * 512);
    }
    __syncthreads();
    short8 af[4], bfr[4];
#pragma unroll
    for (int m = 0; m < 4; m++)
      af[m] = *(const short8*)(lA + (wr * 64 + m * 16 + (lane & 15)) * 32 + (lane >> 4) * 8);
#pragma unroll
    for (int n = 0; n < 4; n++)
      bfr[n] = *(const short8*)(lB + (wc * 64 + n * 16 + (lane & 15)) * 32 + (lane >> 4) * 8);
#pragma unroll
    for (int m = 0; m < 4; m++)
#pragma unroll
      for (int n = 0; n < 4; n++)
        acc[m][n] = __builtin_amdgcn_mfma_f32_16x16x32_bf16(af[m], bfr[n], acc[m][n], 0, 0, 0);
    __syncthreads();
  }
  // epilogue: C/D layout col=lane&15, row=(lane>>4)*4+j
#pragma unroll
  for (int m = 0; m < 4; m++) {
#pragma unroll
    for (int n = 0; n < 4; n++) {
      size_t r = row0 + wr * 64 + m * 16 + (lane >> 4) * 4;
      size_t c = col0 + wc * 64 + n * 16 + (lane & 15);
#pragma unroll
      for (int j = 0; j < 4; j++) {
        if constexpr (sizeof(OutT) == 2)
          Cc[(r + j) * N + c] = f2bf(acc[m][n][j]);
        else
          Cc[(r + j) * N + c] = acc[m][n][j];
      }
    }
  }
}

// ---------------- fused RoPE + RMSNorm: (B,T,NHEADS,HD) bf16 -> (B,NHEADS,T,HD) bf16 ----------------
// one wave per (b,t,h); outscale folds attention 1/sqrt(HD) into Q
template <int NHEADS>
__global__ void ropenorm(const unsigned short* __restrict__ qin, const float* __restrict__ cosp,
                         const float* __restrict__ sinp, unsigned short* __restrict__ qout,
                         float outscale) {
  int gid = blockIdx.x * 4 + (threadIdx.x >> 6);
  int lane = threadIdx.x & 63;
  int h = gid % NHEADS;
  int bt = gid / NHEADS;
  int t = bt % T_SEQ, b = bt / T_SEQ;
  const unsigned short* src = qin + ((size_t)(b * T_SEQ + t) * NHEADS + h) * HD;
  float x1 = bf2f(src[lane]), x2 = bf2f(src[64 + lane]);
  float c = cosp[t * 64 + lane], s = sinp[t * 64 + lane];
  float y1 = x1 * c + x2 * s;
  float y2 = x2 * c - x1 * s;
  float ss = y1 * y1 + y2 * y2;
#pragma unroll
  for (int d = 1; d < 64; d <<= 1) ss += __shfl_xor(ss, d);
  float r = rsqrtf(ss * (1.f / 128.f) + 1e-6f) * outscale;
  unsigned short* dst = qout + ((size_t)(b * NHEADS + h) * T_SEQ + t) * HD;
  dst[lane] = f2bf(y1 * r);
  dst[64 + lane] = f2bf(y2 * r);
}

// ---------------- flash attention ----------------
// grid (T/64, B*NH), 256 thr = 4 waves, wave w owns q rows [q0+16w, q0+16w+16)
// Q: (B,NH,T,D) bf16 (pre-scaled); K: (B,NKV,T,D) bf16; V: (B,NKV,D,T) bf16; Y: (B,T,NH,D) bf16
__global__ __launch_bounds__(256, 2) void attn(const unsigned short* __restrict__ Qn,
                                               const unsigned short* __restrict__ Kn,
                                               const unsigned short* __restrict__ Vt,
                                               unsigned short* __restrict__ Y) {
  __shared__ alignas(16) unsigned short pl[4][16][72];  // per-wave P tile, padded stride
  int qt = blockIdx.x, bh = blockIdx.y;
  int b = bh >> 4, h = bh & 15, kvh = h >> 2;
  int lane = threadIdx.x & 63, w = threadIdx.x >> 6;
  int q0 = qt * 64;
  int qrow = q0 + w * 16;
  const unsigned short* Qp = Qn + ((size_t)(b * NH + h) * T_SEQ + qrow) * HD;
  const unsigned short* Kp = Kn + (size_t)(b * NKV + kvh) * T_SEQ * HD;
  const unsigned short* Vp = Vt + (size_t)(b * NKV + kvh) * HD * T_SEQ;
  const int r16 = lane & 15, q4 = lane >> 4;

  short8 qf[4];
#pragma unroll
  for (int i = 0; i < 4; i++) qf[i] = *(const short8*)(Qp + r16 * HD + i * 32 + q4 * 8);

  f32x4 zero = {0.f, 0.f, 0.f, 0.f};
  f32x4 o[8];
#pragma unroll
  for (int nb = 0; nb < 8; nb++) o[nb] = zero;
  float mrow[4] = {-1e30f, -1e30f, -1e30f, -1e30f};
  float lrow[4] = {0.f, 0.f, 0.f, 0.f};

  for (int kv0 = 0; kv0 <= q0; kv0 += 64) {
    // S = Q K^T  (scale pre-folded into Q)
    f32x4 s[4];
#pragma unroll
    for (int nt = 0; nt < 4; nt++) {
      f32x4 a = zero;
      const unsigned short* kp = Kp + (size_t)(kv0 + nt * 16 + r16) * HD + q4 * 8;
#pragma unroll
      for (int i = 0; i < 4; i++) {
        short8 kf = *(const short8*)(kp + i * 32);
        a = __builtin_amdgcn_mfma_f32_16x16x32_bf16(qf[i], kf, a, 0, 0, 0);
      }
      s[nt] = a;
    }
    if (kv0 == q0) {  // diagonal tile: causal mask
#pragma unroll
      for (int nt = 0; nt < 4; nt++)
#pragma unroll
        for (int j = 0; j < 4; j++) {
          int col = nt * 16 + r16;
          int row = w * 16 + q4 * 4 + j;
          if (col > row) s[nt][j] = -1e30f;
        }
    }
    // online softmax (rows live in 16-lane col groups)
    float alpha[4];
#pragma unroll
    for (int j = 0; j < 4; j++) {
      float v = fmaxf(fmaxf(s[0][j], s[1][j]), fmaxf(s[2][j], s[3][j]));
#pragma unroll
      for (int d = 1; d < 16; d <<= 1) v = fmaxf(v, __shfl_xor(v, d));
      float mn = fmaxf(mrow[j], v);
      alpha[j] = __expf(mrow[j] - mn);
      mrow[j] = mn;
    }
    float rs[4] = {0.f, 0.f, 0.f, 0.f};
#pragma unroll
    for (int nt = 0; nt < 4; nt++)
#pragma unroll
      for (int j = 0; j < 4; j++) {
        float p = __expf(s[nt][j] - mrow[j]);
        s[nt][j] = p;
        rs[j] += p;
      }
#pragma unroll
    for (int j = 0; j < 4; j++) {
      float v = rs[j];
#pragma unroll
      for (int d = 1; d < 16; d <<= 1) v += __shfl_xor(v, d);
      lrow[j] = lrow[j] * alpha[j] + v;
    }
#pragma unroll
    for (int nb = 0; nb < 8; nb++)
#pragma unroll
      for (int j = 0; j < 4; j++) o[nb][j] *= alpha[j];
    // P -> LDS (bf16), per-wave region, in-wave DS ordering => no barrier
#pragma unroll
    for (int nt = 0; nt < 4; nt++)
#pragma unroll
      for (int j = 0; j < 4; j++)
        pl[w][q4 * 4 + j][nt * 16 + r16] = f2bf(s[nt][j]);
    // PV
#pragma unroll
    for (int ks = 0; ks < 2; ks++) {
      short8 pf = *(const short8*)(&pl[w][r16][ks * 32 + q4 * 8]);
#pragma unroll
      for (int nb = 0; nb < 8; nb++) {
        const unsigned short* vp = Vp + (size_t)(nb * 16 + r16) * T_SEQ + kv0 + ks * 32 + q4 * 8;
        short8 vf = *(const short8*)vp;
        o[nb] = __builtin_amdgcn_mfma_f32_16x16x32_bf16(pf, vf, o[nb], 0, 0, 0);
      }
    }
  }
  // epilogue: normalize and write Y (B,T,NH,D)
#pragma unroll
  for (int j = 0; j < 4; j++) lrow[j] = 1.f / lrow[j];
#pragma unroll
  for (int nb = 0; nb < 8; nb++)
#pragma unroll
    for (int j = 0; j < 4; j++) {
      size_t row = (size_t)q0 + w * 16 + q4 * 4 + j;
      Y[((size_t)(b * T_SEQ) + row) * (NH * HD) + h * HD + nb * 16 + r16] = f2bf(o[nb][j] * lrow[j]);
    }
}

extern "C" void kernel_launch(void* const* d_in, const int* in_sizes, int n_in,
                              void* d_out, int out_size, void* d_ws, size_t ws_size,
                              hipStream_t stream) {
  const float* x = (const float*)d_in[0];
  const float* cosp = (const float*)d_in[1];
  const float* sinp = (const float*)d_in[2];
  const float* Wq = (const float*)d_in[3];
  const float* Wk = (const float*)d_in[4];
  const float* Wv = (const float*)d_in[5];
  const float* Wo = (const float*)d_in[6];
  float* out = (float*)d_out;

  char* ws = (char*)d_ws;
  size_t off = 0;
  auto alloc = [&](size_t bytes) { void* p = ws + off; off += bytes; return p; };
  const size_t BT = (size_t)B_SZ * T_SEQ;  // 8192
  unsigned short* xb = (unsigned short*)alloc(BT * C_DIM * 2);
  unsigned short* WqT = (unsigned short*)alloc((size_t)2048 * 2048 * 2);
  unsigned short* WkT = (unsigned short*)alloc((size_t)512 * 2048 * 2);
  unsigned short* WvT = (unsigned short*)alloc((size_t)512 * 2048 * 2);
  unsigned short* WoT = (unsigned short*)alloc((size_t)2048 * 2048 * 2);
  unsigned short* qb = (unsigned short*)alloc(BT * 2048 * 2);
  unsigned short* kb = (unsigned short*)alloc(BT * 512 * 2);
  unsigned short* vb = (unsigned short*)alloc(BT * 512 * 2);
  unsigned short* Qb = (unsigned short*)alloc(BT * 2048 * 2);
  unsigned short* Kb = (unsigned short*)alloc(BT * 512 * 2);
  unsigned short* Vb = (unsigned short*)alloc(BT * 512 * 2);
  unsigned short* Yb = qb;  // alias: qb dead after ropenorm<16>

  dim3 tb(32, 8);
  cast_x<<<16384, 256, 0, stream>>>(x, xb, (int)(BT * C_DIM / 4));
  wtrans<<<dim3(64, 64), tb, 0, stream>>>(Wq, WqT, 2048, 2048);
  wtrans<<<dim3(64, 16), tb, 0, stream>>>(Wk, WkT, 2048, 512);
  wtrans<<<dim3(64, 16), tb, 0, stream>>>(Wv, WvT, 2048, 512);
  wtrans<<<dim3(64, 64), tb, 0, stream>>>(Wo, WoT, 2048, 2048);

  gemm_bt<unsigned short><<<dim3(64, 16), 256, 0, stream>>>(xb, WqT, qb, 8192, 2048, 2048);
  gemm_bt<unsigned short><<<dim3(64, 4), 256, 0, stream>>>(xb, WkT, kb, 8192, 512, 2048);
  gemm_bt<unsigned short><<<dim3(64, 4), 256, 0, stream>>>(xb, WvT, vb, 8192, 512, 2048);

  ropenorm<NH><<<(B_SZ * T_SEQ * NH) / 4, 256, 0, stream>>>(qb, cosp, sinp, Qb,
                                                            0.08838834764831845f);  // 1/sqrt(128)
  ropenorm<NKV><<<(B_SZ * T_SEQ * NKV) / 4, 256, 0, stream>>>(kb, cosp, sinp, Kb, 1.0f);
  vtrans<<<dim3(64, 4, 16), tb, 0, stream>>>(vb, Vb);

  attn<<<dim3(T_SEQ / 64, B_SZ * NH), 256, 0, stream>>>(Qb, Kb, Vb, Yb);

  gemm_bt<float><<<dim3(64, 16), 256, 0, stream>>>(Yb, WoT, out, 8192, 2048, 2048);
}

// Round 3
// 465.343 us; speedup vs baseline: 2.5301x; 2.5301x over previous
//
#include <hip/hip_runtime.h>
#include <hip/hip_bf16.h>

typedef __attribute__((ext_vector_type(8))) short short8;
typedef __attribute__((ext_vector_type(4))) float f32x4;

#define B_SZ 4
#define T_SEQ 2048
#define C_DIM 2048
#define NH 16
#define NKV 4
#define HD 128

__device__ __forceinline__ unsigned short f2bf(float f) {
  union { __hip_bfloat16 h; unsigned short u; } v;
  v.h = __float2bfloat16(f);
  return v.u;
}
__device__ __forceinline__ float bf2f(unsigned short u) {
  union { unsigned short u; __hip_bfloat16 h; } v;
  v.u = u;
  return __bfloat162float(v.h);
}

__device__ __forceinline__ void gload_lds16(const unsigned short* g, unsigned short* l) {
  __builtin_amdgcn_global_load_lds(
      (const __attribute__((address_space(1))) unsigned int*)g,
      (__attribute__((address_space(3))) unsigned int*)l, 16, 0, 0);
}

// ---------------- cast x (fp32 -> bf16), vectorized ----------------
__global__ void cast_x(const float* __restrict__ x, unsigned short* __restrict__ xb, int n4) {
  int i = blockIdx.x * blockDim.x + threadIdx.x;
  if (i < n4) {
    float4 f = ((const float4*)x)[i];
    ushort4 u = make_ushort4(f2bf(f.x), f2bf(f.y), f2bf(f.z), f2bf(f.w));
    ((ushort4*)xb)[i] = u;
  }
}

// ---------------- weight transpose+cast: W (K x N) fp32 -> Wt (N x K) bf16 ----------------
__global__ void wtrans(const float* __restrict__ W, unsigned short* __restrict__ Wt, int K, int N) {
  __shared__ float tile[32][33];
  int k0 = blockIdx.x * 32, n0 = blockIdx.y * 32;
  int tx = threadIdx.x, ty = threadIdx.y;
#pragma unroll
  for (int i = 0; i < 4; i++)
    tile[ty + i * 8][tx] = W[(size_t)(k0 + ty + i * 8) * N + n0 + tx];
  __syncthreads();
#pragma unroll
  for (int i = 0; i < 4; i++)
    Wt[(size_t)(n0 + ty + i * 8) * K + k0 + tx] = f2bf(tile[tx][ty + i * 8]);
}

// ---------------- V transpose: qkv (B,T,3072) cols [2560+kvh*128+d] -> Vt (B,KVH,D,T) bf16 ----------------
__global__ void vtrans(const unsigned short* __restrict__ qkv, unsigned short* __restrict__ Vt) {
  __shared__ unsigned short tile[32][34];
  int t0 = blockIdx.x * 32, d0 = blockIdx.y * 32;
  int b = blockIdx.z >> 2, kvh = blockIdx.z & 3;
  int tx = threadIdx.x, ty = threadIdx.y;
#pragma unroll
  for (int i = 0; i < 4; i++)
    tile[ty + i * 8][tx] =
        qkv[(size_t)(b * T_SEQ + t0 + ty + i * 8) * 3072 + 2560 + kvh * HD + d0 + tx];
  __syncthreads();
#pragma unroll
  for (int i = 0; i < 4; i++)
    Vt[((size_t)(b * NKV + kvh) * HD + d0 + ty + i * 8) * T_SEQ + t0 + tx] = tile[tx][ty + i * 8];
}

// ---------------- GEMM: C[M,N] = A[M,K] * Bt[N,K]^T, bf16 in, OutT out ----------------
template <typename OutT>
__global__ __launch_bounds__(256, 2) void gemm_bt(const unsigned short* __restrict__ A,
                                                  const unsigned short* __restrict__ Bt,
                                                  OutT* __restrict__ Cc, int M, int N, int K) {
  __shared__ alignas(16) unsigned short lA[128 * 32];
  __shared__ alignas(16) unsigned short lB[128 * 32];
  const int tid = threadIdx.x, lane = tid & 63, wid = tid >> 6;
  const int wr = wid >> 1, wc = wid & 1;
  const size_t row0 = (size_t)blockIdx.x * 128, col0 = (size_t)blockIdx.y * 128;
  const int lr = lane >> 2, lc = (lane & 3) * 8;
  f32x4 zero = {0.f, 0.f, 0.f, 0.f};
  f32x4 acc[4][4];
#pragma unroll
  for (int m = 0; m < 4; m++)
#pragma unroll
    for (int n = 0; n < 4; n++) acc[m][n] = zero;

  for (int k0 = 0; k0 < K; k0 += 32) {
#pragma unroll
    for (int j = 0; j < 2; ++j) {
      int chunk = wid * 2 + j;
      gload_lds16(A + (row0 + chunk * 16 + lr) * K + k0 + lc, lA + chunk * 512);
      gload_lds16(Bt + (col0 + chunk * 16 + lr) * K + k0 + lc, lB + chunk * 512);
    }
    __syncthreads();
    short8 af[4], bfr[4];
#pragma unroll
    for (int m = 0; m < 4; m++)
      af[m] = *(const short8*)(lA + (wr * 64 + m * 16 + (lane & 15)) * 32 + (lane >> 4) * 8);
#pragma unroll
    for (int n = 0; n < 4; n++)
      bfr[n] = *(const short8*)(lB + (wc * 64 + n * 16 + (lane & 15)) * 32 + (lane >> 4) * 8);
#pragma unroll
    for (int m = 0; m < 4; m++)
#pragma unroll
      for (int n = 0; n < 4; n++)
        acc[m][n] = __builtin_amdgcn_mfma_f32_16x16x32_bf16(af[m], bfr[n], acc[m][n], 0, 0, 0);
    __syncthreads();
  }
#pragma unroll
  for (int m = 0; m < 4; m++) {
#pragma unroll
    for (int n = 0; n < 4; n++) {
      size_t r = row0 + wr * 64 + m * 16 + (lane >> 4) * 4;
      size_t c = col0 + wc * 64 + n * 16 + (lane & 15);
#pragma unroll
      for (int j = 0; j < 4; j++) {
        if constexpr (sizeof(OutT) == 2)
          Cc[(r + j) * N + c] = f2bf(acc[m][n][j]);
        else
          Cc[(r + j) * N + c] = acc[m][n][j];
      }
    }
  }
}

// ---------------- fused RoPE + RMSNorm from qkv buffer ----------------
// src col base: 0 for Q (h in 0..15), 2048 for K (h in 0..3). out (B,NHEADS,T,HD)
template <int NHEADS>
__global__ void ropenorm(const unsigned short* __restrict__ qkv, int colbase,
                         const float* __restrict__ cosp, const float* __restrict__ sinp,
                         unsigned short* __restrict__ qout, float outscale) {
  int gid = blockIdx.x * 4 + (threadIdx.x >> 6);
  int lane = threadIdx.x & 63;
  int h = gid % NHEADS;
  int bt = gid / NHEADS;
  int t = bt % T_SEQ, b = bt / T_SEQ;
  const unsigned short* src = qkv + (size_t)(b * T_SEQ + t) * 3072 + colbase + h * HD;
  float x1 = bf2f(src[lane]), x2 = bf2f(src[64 + lane]);
  float c = cosp[t * 64 + lane], s = sinp[t * 64 + lane];
  float y1 = x1 * c + x2 * s;
  float y2 = x2 * c - x1 * s;
  float ss = y1 * y1 + y2 * y2;
#pragma unroll
  for (int d = 1; d < 64; d <<= 1) ss += __shfl_xor(ss, d);
  float r = rsqrtf(ss * (1.f / 128.f) + 1e-6f) * outscale;
  unsigned short* dst = qout + ((size_t)(b * NHEADS + h) * T_SEQ + t) * HD;
  dst[lane] = f2bf(y1 * r);
  dst[64 + lane] = f2bf(y2 * r);
}

// ---------------- flash attention, LDS-staged double-buffered K/V ----------------
// 1024 blocks (XCD-pinned decode), 256 thr = 4 waves; block covers 128 q rows of one (b,h);
// wave w owns rows [Q0+32w, Q0+32w+32). KV tiles of 64, K/V in LDS (XOR-swizzled via
// per-lane pre-swizzled global source addresses), double-buffered with global_load_lds.
// Q: (B,NH,T,D) bf16 pre-scaled; K: (B,NKV,T,D); V: (B,NKV,D,T); Y: (B,T,NH*D) bf16
__global__ __launch_bounds__(256, 2) void attn(const unsigned short* __restrict__ Qn,
                                               const unsigned short* __restrict__ Kn,
                                               const unsigned short* __restrict__ Vt,
                                               unsigned short* __restrict__ Y) {
  __shared__ alignas(16) unsigned short lK[2][64 * 128];
  __shared__ alignas(16) unsigned short lV[2][128 * 64];
  __shared__ alignas(16) unsigned short pl[4][32 * 64];

  // XCD-pinned decode: combo c=(b,kvh) -> xcd c&7; 64 blocks per combo (4 heads x 16 qt)
  int lin = blockIdx.x;
  int low3 = lin & 7, rest = lin >> 3;
  int chi = rest >> 6, idx = rest & 63;
  int c = (chi << 3) | low3;  // 0..15
  int b = c >> 2, kvh = c & 3;
  int h = kvh * 4 + (idx >> 4);
  int qt = idx & 15;
  int Q0 = qt * 128;

  int lane = threadIdx.x & 63, w = threadIdx.x >> 6;
  const int r16 = lane & 15, q4 = lane >> 4;
  const unsigned short* Qp = Qn + ((size_t)(b * NH + h) * T_SEQ + Q0 + w * 32) * HD;
  const unsigned short* Kp = Kn + (size_t)(b * NKV + kvh) * T_SEQ * HD;
  const unsigned short* Vp = Vt + (size_t)(b * NKV + kvh) * HD * T_SEQ;

  short8 qf[2][4];
#pragma unroll
  for (int m = 0; m < 2; m++)
#pragma unroll
    for (int i = 0; i < 4; i++)
      qf[m][i] = *(const short8*)(Qp + (m * 16 + r16) * HD + i * 32 + q4 * 8);

  f32x4 zero = {0.f, 0.f, 0.f, 0.f};
  f32x4 o[2][8];
  float mrow[2][4], lrow[2][4];
#pragma unroll
  for (int m = 0; m < 2; m++) {
#pragma unroll
    for (int nb = 0; nb < 8; nb++) o[m][nb] = zero;
#pragma unroll
    for (int j = 0; j < 4; j++) { mrow[m][j] = -1e30f; lrow[m][j] = 0.f; }
  }

  // lK layout: [64 rows][128 shorts]; chunk of 512 shorts = 4 rows x 16 blocks(8 shorts).
  // LDS is written LINEARLY (lane*16B); the XOR swizzle is applied to the GLOBAL source
  // column block (cb ^ (row&7)), so physical block p of row holds logical block p^(row&7).
  auto stageK = [&](int kv0, int buf) {
#pragma unroll
    for (int j = 0; j < 4; ++j) {
      int cw = w * 4 + j;             // chunk 0..15
      int row = cw * 4 + (lane >> 4); // 0..63
      int cb = lane & 15;             // col block (8 shorts)
      gload_lds16(Kp + (size_t)(kv0 + row) * HD + ((cb ^ (row & 7)) * 8), &lK[buf][cw * 512]);
    }
  };
  // lV layout: [128 rows][64 shorts]; chunk of 512 shorts = 8 rows x 8 blocks(8 shorts).
  auto stageV = [&](int kv0, int buf) {
#pragma unroll
    for (int j = 0; j < 4; ++j) {
      int cw = w * 4 + j;
      int row = cw * 8 + (lane >> 3); // 0..127 (d-dim)
      int db = lane & 7;              // t block (8 shorts)
      gload_lds16(Vp + (size_t)row * T_SEQ + kv0 + ((db ^ (row & 7)) * 8), &lV[buf][cw * 512]);
    }
  };

  const int ntiles = 2 * qt + 2;
  const int ntw = (Q0 + w * 32 + 95) >> 6;  // this wave's active tile count

  stageK(0, 0);
  stageV(0, 0);
  __syncthreads();  // drains vmcnt
  int cur = 0;

  for (int t = 0; t < ntiles; ++t) {
    int kv0 = t * 64;
    if (t + 1 < ntiles) { stageK(kv0 + 64, cur ^ 1); stageV(kv0 + 64, cur ^ 1); }
    if (t < ntw) {
      // ---- QK^T ----
      f32x4 s[2][4];
#pragma unroll
      for (int nt = 0; nt < 4; nt++) {
        f32x4 a0 = zero, a1 = zero;
        int krow = nt * 16 + r16;
#pragma unroll
        for (int i = 0; i < 4; i++) {
          short8 kf =
              *(const short8*)(&lK[cur][krow * 128 + ((q4 * 8 + i * 32) ^ ((krow & 7) << 3))]);
          a0 = __builtin_amdgcn_mfma_f32_16x16x32_bf16(qf[0][i], kf, a0, 0, 0, 0);
          a1 = __builtin_amdgcn_mfma_f32_16x16x32_bf16(qf[1][i], kf, a1, 0, 0, 0);
        }
        s[0][nt] = a0;
        s[1][nt] = a1;
      }
      // ---- causal mask (only near-diagonal tiles) ----
      if (kv0 + 63 > Q0 + w * 32) {
#pragma unroll
        for (int m = 0; m < 2; m++)
#pragma unroll
          for (int nt = 0; nt < 4; nt++)
#pragma unroll
            for (int j = 0; j < 4; j++) {
              int col = kv0 + nt * 16 + r16;
              int row = Q0 + w * 32 + m * 16 + q4 * 4 + j;
              if (col > row) s[m][nt][j] = -1e30f;
            }
      }
      // ---- online softmax + P write ----
#pragma unroll
      for (int m = 0; m < 2; m++) {
        float alpha[4];
#pragma unroll
        for (int j = 0; j < 4; j++) {
          float v = fmaxf(fmaxf(s[m][0][j], s[m][1][j]), fmaxf(s[m][2][j], s[m][3][j]));
#pragma unroll
          for (int d = 1; d < 16; d <<= 1) v = fmaxf(v, __shfl_xor(v, d));
          float mn = fmaxf(mrow[m][j], v);
          alpha[j] = __expf(mrow[m][j] - mn);
          mrow[m][j] = mn;
        }
        float rs[4] = {0.f, 0.f, 0.f, 0.f};
#pragma unroll
        for (int nt = 0; nt < 4; nt++)
#pragma unroll
          for (int j = 0; j < 4; j++) {
            float p = __expf(s[m][nt][j] - mrow[m][j]);
            s[m][nt][j] = p;
            rs[j] += p;
          }
#pragma unroll
        for (int j = 0; j < 4; j++) {
          float v = rs[j];
#pragma unroll
          for (int d = 1; d < 16; d <<= 1) v += __shfl_xor(v, d);
          lrow[m][j] = lrow[m][j] * alpha[j] + v;
        }
#pragma unroll
        for (int nb = 0; nb < 8; nb++)
#pragma unroll
          for (int j = 0; j < 4; j++) o[m][nb][j] *= alpha[j];
#pragma unroll
        for (int nt = 0; nt < 4; nt++)
#pragma unroll
          for (int j = 0; j < 4; j++) {
            int prow = m * 16 + q4 * 4 + j;
            pl[w][prow * 64 + ((nt * 16 + r16) ^ ((prow & 7) << 3))] = f2bf(s[m][nt][j]);
          }
      }
      // ---- PV ----
#pragma unroll
      for (int ks = 0; ks < 2; ks++) {
        int t0 = ks * 32 + q4 * 8;
        int prow0 = r16, prow1 = 16 + r16;
        short8 pf0 = *(const short8*)(&pl[w][prow0 * 64 + (t0 ^ ((prow0 & 7) << 3))]);
        short8 pf1 = *(const short8*)(&pl[w][prow1 * 64 + (t0 ^ ((prow1 & 7) << 3))]);
#pragma unroll
        for (int nb = 0; nb < 8; nb++) {
          int vrow = nb * 16 + r16;
          short8 vf = *(const short8*)(&lV[cur][vrow * 64 + (t0 ^ ((vrow & 7) << 3))]);
          o[0][nb] = __builtin_amdgcn_mfma_f32_16x16x32_bf16(pf0, vf, o[0][nb], 0, 0, 0);
          o[1][nb] = __builtin_amdgcn_mfma_f32_16x16x32_bf16(pf1, vf, o[1][nb], 0, 0, 0);
        }
      }
    }
    __syncthreads();  // staging of t+1 complete, all readers of cur done
    cur ^= 1;
  }

  // ---- epilogue ----
#pragma unroll
  for (int m = 0; m < 2; m++) {
#pragma unroll
    for (int j = 0; j < 4; j++) lrow[m][j] = 1.f / lrow[m][j];
#pragma unroll
    for (int nb = 0; nb < 8; nb++)
#pragma unroll
      for (int j = 0; j < 4; j++) {
        size_t row = (size_t)Q0 + w * 32 + m * 16 + q4 * 4 + j;
        Y[((size_t)(b * T_SEQ) + row) * (NH * HD) + h * HD + nb * 16 + r16] =
            f2bf(o[m][nb][j] * lrow[m][j]);
      }
  }
}

extern "C" void kernel_launch(void* const* d_in, const int* in_sizes, int n_in,
                              void* d_out, int out_size, void* d_ws, size_t ws_size,
                              hipStream_t stream) {
  const float* x = (const float*)d_in[0];
  const float* cosp = (const float*)d_in[1];
  const float* sinp = (const float*)d_in[2];
  const float* Wq = (const float*)d_in[3];
  const float* Wk = (const float*)d_in[4];
  const float* Wv = (const float*)d_in[5];
  const float* Wo = (const float*)d_in[6];
  float* out = (float*)d_out;

  char* ws = (char*)d_ws;
  size_t off = 0;
  auto alloc = [&](size_t bytes) { void* p = ws + off; off += bytes; return p; };
  const size_t BT = (size_t)B_SZ * T_SEQ;  // 8192
  unsigned short* xb = (unsigned short*)alloc(BT * C_DIM * 2);                 // 32MB
  unsigned short* WqkvT = (unsigned short*)alloc((size_t)3072 * 2048 * 2);     // 12.6MB
  unsigned short* WoT = (unsigned short*)alloc((size_t)2048 * 2048 * 2);       // 8.4MB
  unsigned short* qkv = (unsigned short*)alloc(BT * 3072 * 2);                 // 48MB
  unsigned short* Kb = (unsigned short*)alloc(BT * 512 * 2);                   // 8MB
  unsigned short* Vb = (unsigned short*)alloc(BT * 512 * 2);                   // 8MB
  unsigned short* Qb = xb;   // alias: xb dead after qkv GEMM
  unsigned short* Yb = qkv;  // alias: qkv dead after ropenorm/vtrans

  dim3 tb(32, 8);
  cast_x<<<16384, 256, 0, stream>>>(x, xb, (int)(BT * C_DIM / 4));
  wtrans<<<dim3(64, 64), tb, 0, stream>>>(Wq, WqkvT, 2048, 2048);
  wtrans<<<dim3(64, 16), tb, 0, stream>>>(Wk, WqkvT + (size_t)2048 * 2048, 2048, 512);
  wtrans<<<dim3(64, 16), tb, 0, stream>>>(Wv, WqkvT + (size_t)2560 * 2048, 2048, 512);
  wtrans<<<dim3(64, 64), tb, 0, stream>>>(Wo, WoT, 2048, 2048);

  gemm_bt<unsigned short><<<dim3(64, 24), 256, 0, stream>>>(xb, WqkvT, qkv, 8192, 3072, 2048);

  ropenorm<NH><<<(B_SZ * T_SEQ * NH) / 4, 256, 0, stream>>>(qkv, 0, cosp, sinp, Qb,
                                                            0.08838834764831845f);  // 1/sqrt(128)
  ropenorm<NKV><<<(B_SZ * T_SEQ * NKV) / 4, 256, 0, stream>>>(qkv, 2048, cosp, sinp, Kb, 1.0f);
  vtrans<<<dim3(64, 4, 16), tb, 0, stream>>>(qkv, Vb);

  attn<<<dim3(1024), 256, 0, stream>>>(Qb, Kb, Vb, Yb);

  gemm_bt<float><<<dim3(64, 16), 256, 0, stream>>>(Yb, WoT, out, 8192, 2048, 2048);
}

// Round 4
// 442.174 us; speedup vs baseline: 2.6627x; 1.0524x over previous
//
#include <hip/hip_runtime.h>
#include <hip/hip_bf16.h>

typedef __attribute__((ext_vector_type(8))) short short8;
typedef __attribute__((ext_vector_type(4))) float f32x4;

#define B_SZ 4
#define T_SEQ 2048
#define C_DIM 2048
#define NH 16
#define NKV 4
#define HD 128

__device__ __forceinline__ unsigned short f2bf(float f) {
  union { __hip_bfloat16 h; unsigned short u; } v;
  v.h = __float2bfloat16(f);
  return v.u;
}
__device__ __forceinline__ float bf2f(unsigned short u) {
  union { unsigned short u; __hip_bfloat16 h; } v;
  v.u = u;
  return __bfloat162float(v.h);
}

__device__ __forceinline__ void gload_lds16(const unsigned short* g, unsigned short* l) {
  __builtin_amdgcn_global_load_lds(
      (const __attribute__((address_space(1))) unsigned int*)g,
      (__attribute__((address_space(3))) unsigned int*)l, 16, 0, 0);
}

// ---------------- cast x (fp32 -> bf16), vectorized ----------------
__global__ void cast_x(const float* __restrict__ x, unsigned short* __restrict__ xb, int n4) {
  int i = blockIdx.x * blockDim.x + threadIdx.x;
  if (i < n4) {
    float4 f = ((const float4*)x)[i];
    ushort4 u = make_ushort4(f2bf(f.x), f2bf(f.y), f2bf(f.z), f2bf(f.w));
    ((ushort4*)xb)[i] = u;
  }
}

// ---------------- weight transpose+cast: W (K x N) fp32 -> Wt (N x K) bf16 ----------------
__global__ void wtrans(const float* __restrict__ W, unsigned short* __restrict__ Wt, int K, int N) {
  __shared__ float tile[32][33];
  int k0 = blockIdx.x * 32, n0 = blockIdx.y * 32;
  int tx = threadIdx.x, ty = threadIdx.y;
#pragma unroll
  for (int i = 0; i < 4; i++)
    tile[ty + i * 8][tx] = W[(size_t)(k0 + ty + i * 8) * N + n0 + tx];
  __syncthreads();
#pragma unroll
  for (int i = 0; i < 4; i++)
    Wt[(size_t)(n0 + ty + i * 8) * K + k0 + tx] = f2bf(tile[tx][ty + i * 8]);
}

// ---------------- V transpose: qkv (B,T,3072) cols [2560+kvh*128+d] -> Vt (B,KVH,D,T) bf16 ----------------
__global__ void vtrans(const unsigned short* __restrict__ qkv, unsigned short* __restrict__ Vt) {
  __shared__ unsigned short tile[32][34];
  int t0 = blockIdx.x * 32, d0 = blockIdx.y * 32;
  int b = blockIdx.z >> 2, kvh = blockIdx.z & 3;
  int tx = threadIdx.x, ty = threadIdx.y;
#pragma unroll
  for (int i = 0; i < 4; i++)
    tile[ty + i * 8][tx] =
        qkv[(size_t)(b * T_SEQ + t0 + ty + i * 8) * 3072 + 2560 + kvh * HD + d0 + tx];
  __syncthreads();
#pragma unroll
  for (int i = 0; i < 4; i++)
    Vt[((size_t)(b * NKV + kvh) * HD + d0 + ty + i * 8) * T_SEQ + t0 + tx] = tile[tx][ty + i * 8];
}

// ---------------- GEMM: C[M,N] = A[M,K] * Bt[N,K]^T, bf16 in, OutT out ----------------
template <typename OutT>
__global__ __launch_bounds__(256, 2) void gemm_bt(const unsigned short* __restrict__ A,
                                                  const unsigned short* __restrict__ Bt,
                                                  OutT* __restrict__ Cc, int M, int N, int K) {
  __shared__ alignas(16) unsigned short lA[128 * 32];
  __shared__ alignas(16) unsigned short lB[128 * 32];
  const int tid = threadIdx.x, lane = tid & 63, wid = tid >> 6;
  const int wr = wid >> 1, wc = wid & 1;
  const size_t row0 = (size_t)blockIdx.x * 128, col0 = (size_t)blockIdx.y * 128;
  const int lr = lane >> 2, lc = (lane & 3) * 8;
  f32x4 zero = {0.f, 0.f, 0.f, 0.f};
  f32x4 acc[4][4];
#pragma unroll
  for (int m = 0; m < 4; m++)
#pragma unroll
    for (int n = 0; n < 4; n++) acc[m][n] = zero;

  for (int k0 = 0; k0 < K; k0 += 32) {
#pragma unroll
    for (int j = 0; j < 2; ++j) {
      int chunk = wid * 2 + j;
      gload_lds16(A + (row0 + chunk * 16 + lr) * K + k0 + lc, lA + chunk * 512);
      gload_lds16(Bt + (col0 + chunk * 16 + lr) * K + k0 + lc, lB + chunk * 512);
    }
    __syncthreads();
    short8 af[4], bfr[4];
#pragma unroll
    for (int m = 0; m < 4; m++)
      af[m] = *(const short8*)(lA + (wr * 64 + m * 16 + (lane & 15)) * 32 + (lane >> 4) * 8);
#pragma unroll
    for (int n = 0; n < 4; n++)
      bfr[n] = *(const short8*)(lB + (wc * 64 + n * 16 + (lane & 15)) * 32 + (lane >> 4) * 8);
#pragma unroll
    for (int m = 0; m < 4; m++)
#pragma unroll
      for (int n = 0; n < 4; n++)
        acc[m][n] = __builtin_amdgcn_mfma_f32_16x16x32_bf16(af[m], bfr[n], acc[m][n], 0, 0, 0);
    __syncthreads();
  }
#pragma unroll
  for (int m = 0; m < 4; m++) {
#pragma unroll
    for (int n = 0; n < 4; n++) {
      size_t r = row0 + wr * 64 + m * 16 + (lane >> 4) * 4;
      size_t c = col0 + wc * 64 + n * 16 + (lane & 15);
#pragma unroll
      for (int j = 0; j < 4; j++) {
        if constexpr (sizeof(OutT) == 2)
          Cc[(r + j) * N + c] = f2bf(acc[m][n][j]);
        else
          Cc[(r + j) * N + c] = acc[m][n][j];
      }
    }
  }
}

// ---------------- fused RoPE + RMSNorm from qkv buffer ----------------
template <int NHEADS>
__global__ void ropenorm(const unsigned short* __restrict__ qkv, int colbase,
                         const float* __restrict__ cosp, const float* __restrict__ sinp,
                         unsigned short* __restrict__ qout, float outscale) {
  int gid = blockIdx.x * 4 + (threadIdx.x >> 6);
  int lane = threadIdx.x & 63;
  int h = gid % NHEADS;
  int bt = gid / NHEADS;
  int t = bt % T_SEQ, b = bt / T_SEQ;
  const unsigned short* src = qkv + (size_t)(b * T_SEQ + t) * 3072 + colbase + h * HD;
  float x1 = bf2f(src[lane]), x2 = bf2f(src[64 + lane]);
  float c = cosp[t * 64 + lane], s = sinp[t * 64 + lane];
  float y1 = x1 * c + x2 * s;
  float y2 = x2 * c - x1 * s;
  float ss = y1 * y1 + y2 * y2;
#pragma unroll
  for (int d = 1; d < 64; d <<= 1) ss += __shfl_xor(ss, d);
  float r = rsqrtf(ss * (1.f / 128.f) + 1e-6f) * outscale;
  unsigned short* dst = qout + ((size_t)(b * NHEADS + h) * T_SEQ + t) * HD;
  dst[lane] = f2bf(y1 * r);
  dst[64 + lane] = f2bf(y2 * r);
}

// P-tile row swizzle: distinguishes the 4 q4 lane-groups (row bits 2-3) so concurrent
// scalar writes of rows {q4*4+j} land on disjoint bank blocks. Bijective per row.
__device__ __forceinline__ int swzP(int row) {
  return (row & 7) ^ (((row >> 3) & 1) << 1);
}

// ---------------- flash attention, LDS-staged double-buffered K/V ----------------
// 1024 blocks (XCD-pinned decode, qt DESCENDING so heavy blocks launch first),
// 256 thr = 4 waves; block covers 128 q rows of one (b,h); wave w owns rows
// [Q0+32w, Q0+32w+32). KV tiles of 64; K/V LDS XOR-swizzled via pre-swizzled global
// source addresses; double-buffered global_load_lds. Online softmax with T13 defer-max
// (THR=8) and per-lane deferred L (single epilogue reduce).
__global__ __launch_bounds__(256, 2) void attn(const unsigned short* __restrict__ Qn,
                                               const unsigned short* __restrict__ Kn,
                                               const unsigned short* __restrict__ Vt,
                                               unsigned short* __restrict__ Y) {
  __shared__ alignas(16) unsigned short lK[2][64 * 128];
  __shared__ alignas(16) unsigned short lV[2][128 * 64];
  __shared__ alignas(16) unsigned short pl[4][32 * 64];

  int lin = blockIdx.x;
  int low3 = lin & 7, rest = lin >> 3;
  int chi = rest >> 6, idx = rest & 63;
  int c = (chi << 3) | low3;  // 0..15 combo (b,kvh), pinned to xcd c&7
  int b = c >> 2, kvh = c & 3;
  int h = kvh * 4 + (idx >> 4);
  int qt = 15 - (idx & 15);  // big blocks dispatch first
  int Q0 = qt * 128;

  int lane = threadIdx.x & 63, w = threadIdx.x >> 6;
  const int r16 = lane & 15, q4 = lane >> 4;
  const unsigned short* Qp = Qn + ((size_t)(b * NH + h) * T_SEQ + Q0 + w * 32) * HD;
  const unsigned short* Kp = Kn + (size_t)(b * NKV + kvh) * T_SEQ * HD;
  const unsigned short* Vp = Vt + (size_t)(b * NKV + kvh) * HD * T_SEQ;

  short8 qf[2][4];
#pragma unroll
  for (int m = 0; m < 2; m++)
#pragma unroll
    for (int i = 0; i < 4; i++)
      qf[m][i] = *(const short8*)(Qp + (m * 16 + r16) * HD + i * 32 + q4 * 8);

  f32x4 zero = {0.f, 0.f, 0.f, 0.f};
  f32x4 o[2][8];
  float mrow[2][4], Lp[2][4];  // Lp: per-lane partial row-sum (reduced in epilogue)
#pragma unroll
  for (int m = 0; m < 2; m++) {
#pragma unroll
    for (int nb = 0; nb < 8; nb++) o[m][nb] = zero;
#pragma unroll
    for (int j = 0; j < 4; j++) { mrow[m][j] = -1e30f; Lp[m][j] = 0.f; }
  }

  // lK layout: [64 rows][128 shorts]; chunk of 512 shorts = 4 rows x 16 blocks(8 shorts).
  // LDS written LINEARLY; XOR swizzle applied to the GLOBAL source column block.
  auto stageK = [&](int kv0, int buf) {
#pragma unroll
    for (int j = 0; j < 4; ++j) {
      int cw = w * 4 + j;
      int row = cw * 4 + (lane >> 4);
      int cb = lane & 15;
      gload_lds16(Kp + (size_t)(kv0 + row) * HD + ((cb ^ (row & 7)) * 8), &lK[buf][cw * 512]);
    }
  };
  // lV layout: [128 rows][64 shorts]; chunk of 512 shorts = 8 rows x 8 blocks(8 shorts).
  auto stageV = [&](int kv0, int buf) {
#pragma unroll
    for (int j = 0; j < 4; ++j) {
      int cw = w * 4 + j;
      int row = cw * 8 + (lane >> 3);
      int db = lane & 7;
      gload_lds16(Vp + (size_t)row * T_SEQ + kv0 + ((db ^ (row & 7)) * 8), &lV[buf][cw * 512]);
    }
  };

  const int ntiles = 2 * qt + 2;
  const int ntw = (Q0 + w * 32 + 95) >> 6;  // this wave's active tile count

  stageK(0, 0);
  stageV(0, 0);
  __syncthreads();
  int cur = 0;

  for (int t = 0; t < ntiles; ++t) {
    int kv0 = t * 64;
    if (t + 1 < ntiles) { stageK(kv0 + 64, cur ^ 1); stageV(kv0 + 64, cur ^ 1); }
    if (t < ntw) {
      // ---- QK^T ----
      f32x4 s[2][4];
      __builtin_amdgcn_s_setprio(1);
#pragma unroll
      for (int nt = 0; nt < 4; nt++) {
        f32x4 a0 = zero, a1 = zero;
        int krow = nt * 16 + r16;
#pragma unroll
        for (int i = 0; i < 4; i++) {
          short8 kf =
              *(const short8*)(&lK[cur][krow * 128 + ((q4 * 8 + i * 32) ^ ((krow & 7) << 3))]);
          a0 = __builtin_amdgcn_mfma_f32_16x16x32_bf16(qf[0][i], kf, a0, 0, 0, 0);
          a1 = __builtin_amdgcn_mfma_f32_16x16x32_bf16(qf[1][i], kf, a1, 0, 0, 0);
        }
        s[0][nt] = a0;
        s[1][nt] = a1;
      }
      __builtin_amdgcn_s_setprio(0);
      // ---- causal mask (only near-diagonal tiles) ----
      if (kv0 + 63 > Q0 + w * 32) {
#pragma unroll
        for (int m = 0; m < 2; m++)
#pragma unroll
          for (int nt = 0; nt < 4; nt++)
#pragma unroll
            for (int j = 0; j < 4; j++) {
              int col = kv0 + nt * 16 + r16;
              int row = Q0 + w * 32 + m * 16 + q4 * 4 + j;
              if (col > row) s[m][nt][j] = -1e30f;
            }
      }
      // ---- tile max (per-lane over nt, then 16-lane reduce) ----
      float pm[2][4];
#pragma unroll
      for (int m = 0; m < 2; m++)
#pragma unroll
        for (int j = 0; j < 4; j++)
          pm[m][j] = fmaxf(fmaxf(s[m][0][j], s[m][1][j]), fmaxf(s[m][2][j], s[m][3][j]));
#pragma unroll
      for (int d = 1; d < 16; d <<= 1)
#pragma unroll
        for (int m = 0; m < 2; m++)
#pragma unroll
          for (int j = 0; j < 4; j++) pm[m][j] = fmaxf(pm[m][j], __shfl_xor(pm[m][j], d));
      float dmax = -1e30f;
#pragma unroll
      for (int m = 0; m < 2; m++)
#pragma unroll
        for (int j = 0; j < 4; j++) dmax = fmaxf(dmax, pm[m][j] - mrow[m][j]);
      // ---- T13 defer-max: rescale only if some row grew by > 8 ----
      if (!__all(dmax <= 8.0f)) {
#pragma unroll
        for (int m = 0; m < 2; m++)
#pragma unroll
          for (int j = 0; j < 4; j++) {
            float mn = fmaxf(mrow[m][j], pm[m][j]);
            float al = __expf(mrow[m][j] - mn);
            mrow[m][j] = mn;
            Lp[m][j] *= al;
#pragma unroll
            for (int nb = 0; nb < 8; nb++) o[m][nb][j] *= al;
          }
      }
      // ---- P = exp(S - mrow), per-lane L accumulate, write P (swizzled) ----
#pragma unroll
      for (int m = 0; m < 2; m++)
#pragma unroll
        for (int nt = 0; nt < 4; nt++)
#pragma unroll
          for (int j = 0; j < 4; j++) {
            float p = __expf(s[m][nt][j] - mrow[m][j]);
            Lp[m][j] += p;
            int prow = m * 16 + q4 * 4 + j;
            pl[w][prow * 64 + ((nt * 16 + r16) ^ (swzP(prow) << 3))] = f2bf(p);
          }
      // ---- PV ----
      __builtin_amdgcn_s_setprio(1);
#pragma unroll
      for (int ks = 0; ks < 2; ks++) {
        int t0 = ks * 32 + q4 * 8;
        int prow0 = r16, prow1 = 16 + r16;
        short8 pf0 = *(const short8*)(&pl[w][prow0 * 64 + (t0 ^ (swzP(prow0) << 3))]);
        short8 pf1 = *(const short8*)(&pl[w][prow1 * 64 + (t0 ^ (swzP(prow1) << 3))]);
#pragma unroll
        for (int nb = 0; nb < 8; nb++) {
          int vrow = nb * 16 + r16;
          short8 vf = *(const short8*)(&lV[cur][vrow * 64 + (t0 ^ ((vrow & 7) << 3))]);
          o[0][nb] = __builtin_amdgcn_mfma_f32_16x16x32_bf16(pf0, vf, o[0][nb], 0, 0, 0);
          o[1][nb] = __builtin_amdgcn_mfma_f32_16x16x32_bf16(pf1, vf, o[1][nb], 0, 0, 0);
        }
      }
      __builtin_amdgcn_s_setprio(0);
    }
    __syncthreads();
    cur ^= 1;
  }

  // ---- epilogue: reduce per-lane L across the 16-lane col group, normalize, store ----
  float linv[2][4];
#pragma unroll
  for (int m = 0; m < 2; m++)
#pragma unroll
    for (int j = 0; j < 4; j++) {
      float v = Lp[m][j];
#pragma unroll
      for (int d = 1; d < 16; d <<= 1) v += __shfl_xor(v, d);
      linv[m][j] = 1.f / v;
    }
#pragma unroll
  for (int m = 0; m < 2; m++)
#pragma unroll
    for (int nb = 0; nb < 8; nb++)
#pragma unroll
      for (int j = 0; j < 4; j++) {
        size_t row = (size_t)Q0 + w * 32 + m * 16 + q4 * 4 + j;
        Y[((size_t)(b * T_SEQ) + row) * (NH * HD) + h * HD + nb * 16 + r16] =
            f2bf(o[m][nb][j] * linv[m][j]);
      }
}

extern "C" void kernel_launch(void* const* d_in, const int* in_sizes, int n_in,
                              void* d_out, int out_size, void* d_ws, size_t ws_size,
                              hipStream_t stream) {
  const float* x = (const float*)d_in[0];
  const float* cosp = (const float*)d_in[1];
  const float* sinp = (const float*)d_in[2];
  const float* Wq = (const float*)d_in[3];
  const float* Wk = (const float*)d_in[4];
  const float* Wv = (const float*)d_in[5];
  const float* Wo = (const float*)d_in[6];
  float* out = (float*)d_out;

  char* ws = (char*)d_ws;
  size_t off = 0;
  auto alloc = [&](size_t bytes) { void* p = ws + off; off += bytes; return p; };
  const size_t BT = (size_t)B_SZ * T_SEQ;  // 8192
  unsigned short* xb = (unsigned short*)alloc(BT * C_DIM * 2);                 // 32MB
  unsigned short* WqkvT = (unsigned short*)alloc((size_t)3072 * 2048 * 2);     // 12.6MB
  unsigned short* WoT = (unsigned short*)alloc((size_t)2048 * 2048 * 2);       // 8.4MB
  unsigned short* qkv = (unsigned short*)alloc(BT * 3072 * 2);                 // 48MB
  unsigned short* Kb = (unsigned short*)alloc(BT * 512 * 2);                   // 8MB
  unsigned short* Vb = (unsigned short*)alloc(BT * 512 * 2);                   // 8MB
  unsigned short* Qb = xb;   // alias: xb dead after qkv GEMM
  unsigned short* Yb = qkv;  // alias: qkv dead after ropenorm/vtrans

  dim3 tb(32, 8);
  cast_x<<<16384, 256, 0, stream>>>(x, xb, (int)(BT * C_DIM / 4));
  wtrans<<<dim3(64, 64), tb, 0, stream>>>(Wq, WqkvT, 2048, 2048);
  wtrans<<<dim3(64, 16), tb, 0, stream>>>(Wk, WqkvT + (size_t)2048 * 2048, 2048, 512);
  wtrans<<<dim3(64, 16), tb, 0, stream>>>(Wv, WqkvT + (size_t)2560 * 2048, 2048, 512);
  wtrans<<<dim3(64, 64), tb, 0, stream>>>(Wo, WoT, 2048, 2048);

  gemm_bt<unsigned short><<<dim3(64, 24), 256, 0, stream>>>(xb, WqkvT, qkv, 8192, 3072, 2048);

  ropenorm<NH><<<(B_SZ * T_SEQ * NH) / 4, 256, 0, stream>>>(qkv, 0, cosp, sinp, Qb,
                                                            0.08838834764831845f);  // 1/sqrt(128)
  ropenorm<NKV><<<(B_SZ * T_SEQ * NKV) / 4, 256, 0, stream>>>(qkv, 2048, cosp, sinp, Kb, 1.0f);
  vtrans<<<dim3(64, 4, 16), tb, 0, stream>>>(qkv, Vb);

  attn<<<dim3(1024), 256, 0, stream>>>(Qb, Kb, Vb, Yb);

  gemm_bt<float><<<dim3(64, 16), 256, 0, stream>>>(Yb, WoT, out, 8192, 2048, 2048);
}

// Round 5
// 434.588 us; speedup vs baseline: 2.7092x; 1.0175x over previous
//
#include <hip/hip_runtime.h>
#include <hip/hip_bf16.h>

typedef __attribute__((ext_vector_type(8))) short short8;
typedef __attribute__((ext_vector_type(4))) float f32x4;

#define B_SZ 4
#define T_SEQ 2048
#define C_DIM 2048
#define NH 16
#define NKV 4
#define HD 128

#define MFMA16 __builtin_amdgcn_mfma_f32_16x16x32_bf16

__device__ __forceinline__ unsigned short f2bf(float f) {
  union { __hip_bfloat16 h; unsigned short u; } v;
  v.h = __float2bfloat16(f);
  return v.u;
}
__device__ __forceinline__ float bf2f(unsigned short u) {
  union { unsigned short u; __hip_bfloat16 h; } v;
  v.u = u;
  return __bfloat162float(v.h);
}

__device__ __forceinline__ void gload_lds16(const unsigned short* g, unsigned short* l) {
  __builtin_amdgcn_global_load_lds(
      (const __attribute__((address_space(1))) unsigned int*)g,
      (__attribute__((address_space(3))) unsigned int*)l, 16, 0, 0);
}

// ---------------- cast x (fp32 -> bf16), vectorized ----------------
__global__ void cast_x(const float* __restrict__ x, unsigned short* __restrict__ xb, int n4) {
  int i = blockIdx.x * blockDim.x + threadIdx.x;
  if (i < n4) {
    float4 f = ((const float4*)x)[i];
    ushort4 u = make_ushort4(f2bf(f.x), f2bf(f.y), f2bf(f.z), f2bf(f.w));
    ((ushort4*)xb)[i] = u;
  }
}

// ---------------- weight transpose+cast: W (K x N) fp32 -> Wt (N x K) bf16 ----------------
__global__ void wtrans(const float* __restrict__ W, unsigned short* __restrict__ Wt, int K, int N) {
  __shared__ float tile[32][33];
  int k0 = blockIdx.x * 32, n0 = blockIdx.y * 32;
  int tx = threadIdx.x, ty = threadIdx.y;
#pragma unroll
  for (int i = 0; i < 4; i++)
    tile[ty + i * 8][tx] = W[(size_t)(k0 + ty + i * 8) * N + n0 + tx];
  __syncthreads();
#pragma unroll
  for (int i = 0; i < 4; i++)
    Wt[(size_t)(n0 + ty + i * 8) * K + k0 + tx] = f2bf(tile[tx][ty + i * 8]);
}

// ---------------- V transpose: qkv (B,T,3072) cols [2560+kvh*128+d] -> Vt (B,KVH,D,T) bf16 ----------------
__global__ void vtrans(const unsigned short* __restrict__ qkv, unsigned short* __restrict__ Vt) {
  __shared__ unsigned short tile[32][34];
  int t0 = blockIdx.x * 32, d0 = blockIdx.y * 32;
  int b = blockIdx.z >> 2, kvh = blockIdx.z & 3;
  int tx = threadIdx.x, ty = threadIdx.y;
#pragma unroll
  for (int i = 0; i < 4; i++)
    tile[ty + i * 8][tx] =
        qkv[(size_t)(b * T_SEQ + t0 + ty + i * 8) * 3072 + 2560 + kvh * HD + d0 + tx];
  __syncthreads();
#pragma unroll
  for (int i = 0; i < 4; i++)
    Vt[((size_t)(b * NKV + kvh) * HD + d0 + ty + i * 8) * T_SEQ + t0 + tx] = tile[tx][ty + i * 8];
}

// ---------------- 256x256 8-phase GEMM: C[M,N] = A[M,K] * Bt[N,K]^T ----------------
// 512 thr = 8 waves (2m x 4n); per-wave C = 128x64 (8 mf x 4 nf fragments).
// LDS 128KB: buf[2] x {A0,A1,B0,B1} halves of 128x64 bf16, XOR-block swizzled via
// pre-swizzled GLOBAL source (write-linear), swizzled ds_read (rule 21 both-sides).
// Schedule/K-tile (BK=64): P0{read a0-3,b01; stage t+1.B0; bar; lgkm0; 16 MFMA; bar}
// P1{read b23; stage t+1.B1; ...} P2{read a4-7; ...} P3{stage t+2.A0,A1; MFMA;
// vmcnt(4 or 0 at tail); bar}. Counted vmcnt: never 0 in steady state (T3+T4).
template <typename OutT>
__global__ __launch_bounds__(512, 2) void gemm256(const unsigned short* __restrict__ A,
                                                  const unsigned short* __restrict__ Bt,
                                                  OutT* __restrict__ Cc, int N, int K, int GX) {
  __shared__ alignas(16) unsigned short lds[2][4][128 * 64];
  const int tid = threadIdx.x, lane = tid & 63, wid = tid >> 6;
  const int wave_m = wid >> 2, wave_n = wid & 3;
  const int r16 = lane & 15, q4 = lane >> 4;
  const int sw = r16 & 7;

  // XCD-bijective remap (m204): consecutive wg on one XCD -> consecutive bx (shared B panel)
  int nwg = gridDim.x, orig = blockIdx.x;
  int qq = nwg >> 3, rr = nwg & 7;
  int xcd = orig & 7, loc = orig >> 3;
  int wg = (xcd < rr ? xcd * (qq + 1) : rr * (qq + 1) + (xcd - rr) * qq) + loc;
  int bx = wg % GX, by = wg / GX;
  const size_t row0 = (size_t)bx * 256, col0 = (size_t)by * 256;

  const unsigned short* Ab0 = A + row0 * K;
  const unsigned short* Ab1 = A + (row0 + 128) * K;
  const unsigned short* Bb0 = Bt + col0 * K;
  const unsigned short* Bb1 = Bt + (col0 + 128) * K;

  const int srow = lane >> 3, spb = lane & 7;
  auto stage = [&](const unsigned short* base, int buf, int slot, int k0) {
#pragma unroll
    for (int j = 0; j < 2; ++j) {
      int cw = j * 8 + wid;     // chunk-group 0..15 (8 rows each)
      int row = cw * 8 + srow;  // 0..127
      gload_lds16(base + (size_t)row * K + k0 + ((spb ^ srow) * 8), &lds[buf][slot][cw * 512]);
    }
  };

  f32x4 acc[8][4];
  f32x4 zero = {0.f, 0.f, 0.f, 0.f};
#pragma unroll
  for (int m = 0; m < 8; m++)
#pragma unroll
    for (int n = 0; n < 4; n++) acc[m][n] = zero;

  const int NT = K / 64;
  // prologue: tile0 fully, tile1 A-halves
  stage(Ab0, 0, 0, 0);
  stage(Ab1, 0, 1, 0);
  stage(Bb0, 0, 2, 0);
  stage(Bb1, 0, 3, 0);
  stage(Ab0, 1, 0, 64);
  stage(Ab1, 1, 1, 64);
  asm volatile("s_waitcnt vmcnt(4)" ::: "memory");
  __builtin_amdgcn_s_barrier();

  short8 af[4][2], b01[2][2], b23[2][2];
  const int bslot = 2 + (wave_n >> 1);
  const int bro = (wave_n & 1) * 64;

  int cur = 0;
#pragma unroll 1
  for (int t = 0; t < NT; ++t) {
    const unsigned short* Ah = &lds[cur][wave_m][0];
    const unsigned short* Bh = &lds[cur][bslot][0];
    const int k1 = t * 64 + 64, k2 = t * 64 + 128;
    // ---- P0: a[0-3] + b[0-1]; stage t+1.B0; MFMA Q(m0-3 x n0-1) ----
#pragma unroll
    for (int mf = 0; mf < 4; mf++)
#pragma unroll
      for (int kk = 0; kk < 2; kk++)
        af[mf][kk] = *(const short8*)(Ah + (mf * 16 + r16) * 64 + (((kk * 4 + q4) ^ sw) * 8));
#pragma unroll
    for (int nf = 0; nf < 2; nf++)
#pragma unroll
      for (int kk = 0; kk < 2; kk++)
        b01[nf][kk] =
            *(const short8*)(Bh + (bro + nf * 16 + r16) * 64 + (((kk * 4 + q4) ^ sw) * 8));
    if (t + 1 < NT) stage(Bb0, cur ^ 1, 2, k1);
    __builtin_amdgcn_s_barrier();
    asm volatile("s_waitcnt lgkmcnt(0)" ::: "memory");
    __builtin_amdgcn_s_setprio(1);
#pragma unroll
    for (int mf = 0; mf < 4; mf++)
#pragma unroll
      for (int nf = 0; nf < 2; nf++)
#pragma unroll
        for (int kk = 0; kk < 2; kk++)
          acc[mf][nf] = MFMA16(af[mf][kk], b01[nf][kk], acc[mf][nf], 0, 0, 0);
    __builtin_amdgcn_s_setprio(0);
    __builtin_amdgcn_s_barrier();
    // ---- P1: b[2-3]; stage t+1.B1; MFMA Q(m0-3 x n2-3) ----
#pragma unroll
    for (int nf = 0; nf < 2; nf++)
#pragma unroll
      for (int kk = 0; kk < 2; kk++)
        b23[nf][kk] =
            *(const short8*)(Bh + (bro + (nf + 2) * 16 + r16) * 64 + (((kk * 4 + q4) ^ sw) * 8));
    if (t + 1 < NT) stage(Bb1, cur ^ 1, 3, k1);
    __builtin_amdgcn_s_barrier();
    asm volatile("s_waitcnt lgkmcnt(0)" ::: "memory");
    __builtin_amdgcn_s_setprio(1);
#pragma unroll
    for (int mf = 0; mf < 4; mf++)
#pragma unroll
      for (int nf = 0; nf < 2; nf++)
#pragma unroll
        for (int kk = 0; kk < 2; kk++)
          acc[mf][nf + 2] = MFMA16(af[mf][kk], b23[nf][kk], acc[mf][nf + 2], 0, 0, 0);
    __builtin_amdgcn_s_setprio(0);
    __builtin_amdgcn_s_barrier();
    // ---- P2: a[4-7] (reuse regs); MFMA Q(m4-7 x n0-1) ----
#pragma unroll
    for (int mf = 0; mf < 4; mf++)
#pragma unroll
      for (int kk = 0; kk < 2; kk++)
        af[mf][kk] =
            *(const short8*)(Ah + ((mf + 4) * 16 + r16) * 64 + (((kk * 4 + q4) ^ sw) * 8));
    __builtin_amdgcn_s_barrier();
    asm volatile("s_waitcnt lgkmcnt(0)" ::: "memory");
    __builtin_amdgcn_s_setprio(1);
#pragma unroll
    for (int mf = 0; mf < 4; mf++)
#pragma unroll
      for (int nf = 0; nf < 2; nf++)
#pragma unroll
        for (int kk = 0; kk < 2; kk++)
          acc[mf + 4][nf] = MFMA16(af[mf][kk], b01[nf][kk], acc[mf + 4][nf], 0, 0, 0);
    __builtin_amdgcn_s_setprio(0);
    __builtin_amdgcn_s_barrier();
    // ---- P3: stage t+2.A0,A1 (A readers done at P2); MFMA Q(m4-7 x n2-3); vmcnt gate ----
    if (t + 2 < NT) {
      stage(Ab0, cur, 0, k2);
      stage(Ab1, cur, 1, k2);
    }
    __builtin_amdgcn_s_barrier();
    __builtin_amdgcn_s_setprio(1);
#pragma unroll
    for (int mf = 0; mf < 4; mf++)
#pragma unroll
      for (int nf = 0; nf < 2; nf++)
#pragma unroll
        for (int kk = 0; kk < 2; kk++)
          acc[mf + 4][nf + 2] = MFMA16(af[mf][kk], b23[nf][kk], acc[mf + 4][nf + 2], 0, 0, 0);
    __builtin_amdgcn_s_setprio(0);
    if (t + 1 < NT) {
      if (t + 2 < NT)
        asm volatile("s_waitcnt vmcnt(4)" ::: "memory");  // t+1 resident; t+2.A in flight
      else
        asm volatile("s_waitcnt vmcnt(0)" ::: "memory");  // final drain
    }
    __builtin_amdgcn_s_barrier();
    cur ^= 1;
  }

  // ---- epilogue ----
#pragma unroll
  for (int mf = 0; mf < 8; mf++)
#pragma unroll
    for (int nf = 0; nf < 4; nf++) {
      size_t rbase = row0 + wave_m * 128 + mf * 16 + q4 * 4;
      size_t cc = col0 + wave_n * 64 + nf * 16 + r16;
#pragma unroll
      for (int jj = 0; jj < 4; jj++) {
        if constexpr (sizeof(OutT) == 2)
          Cc[(rbase + jj) * (size_t)N + cc] = f2bf(acc[mf][nf][jj]);
        else
          Cc[(rbase + jj) * (size_t)N + cc] = acc[mf][nf][jj];
      }
    }
}

// ---------------- fused RoPE + RMSNorm from qkv buffer ----------------
template <int NHEADS>
__global__ void ropenorm(const unsigned short* __restrict__ qkv, int colbase,
                         const float* __restrict__ cosp, const float* __restrict__ sinp,
                         unsigned short* __restrict__ qout, float outscale) {
  int gid = blockIdx.x * 4 + (threadIdx.x >> 6);
  int lane = threadIdx.x & 63;
  int h = gid % NHEADS;
  int bt = gid / NHEADS;
  int t = bt % T_SEQ, b = bt / T_SEQ;
  const unsigned short* src = qkv + (size_t)(b * T_SEQ + t) * 3072 + colbase + h * HD;
  float x1 = bf2f(src[lane]), x2 = bf2f(src[64 + lane]);
  float c = cosp[t * 64 + lane], s = sinp[t * 64 + lane];
  float y1 = x1 * c + x2 * s;
  float y2 = x2 * c - x1 * s;
  float ss = y1 * y1 + y2 * y2;
#pragma unroll
  for (int d = 1; d < 64; d <<= 1) ss += __shfl_xor(ss, d);
  float r = rsqrtf(ss * (1.f / 128.f) + 1e-6f) * outscale;
  unsigned short* dst = qout + ((size_t)(b * NHEADS + h) * T_SEQ + t) * HD;
  dst[lane] = f2bf(y1 * r);
  dst[64 + lane] = f2bf(y2 * r);
}

// P-tile row swizzle (keeps concurrent q4-group writes on disjoint bank blocks)
__device__ __forceinline__ int swzP(int row) {
  return (row & 7) ^ (((row >> 3) & 1) << 1);
}

// ---------------- flash attention (unchanged from round 4) ----------------
__global__ __launch_bounds__(256, 2) void attn(const unsigned short* __restrict__ Qn,
                                               const unsigned short* __restrict__ Kn,
                                               const unsigned short* __restrict__ Vt,
                                               unsigned short* __restrict__ Y) {
  __shared__ alignas(16) unsigned short lK[2][64 * 128];
  __shared__ alignas(16) unsigned short lV[2][128 * 64];
  __shared__ alignas(16) unsigned short pl[4][32 * 64];

  int lin = blockIdx.x;
  int low3 = lin & 7, rest = lin >> 3;
  int chi = rest >> 6, idx = rest & 63;
  int c = (chi << 3) | low3;  // 0..15 combo (b,kvh), pinned to xcd c&7
  int b = c >> 2, kvh = c & 3;
  int h = kvh * 4 + (idx >> 4);
  int qt = 15 - (idx & 15);  // big blocks dispatch first
  int Q0 = qt * 128;

  int lane = threadIdx.x & 63, w = threadIdx.x >> 6;
  const int r16 = lane & 15, q4 = lane >> 4;
  const unsigned short* Qp = Qn + ((size_t)(b * NH + h) * T_SEQ + Q0 + w * 32) * HD;
  const unsigned short* Kp = Kn + (size_t)(b * NKV + kvh) * T_SEQ * HD;
  const unsigned short* Vp = Vt + (size_t)(b * NKV + kvh) * HD * T_SEQ;

  short8 qf[2][4];
#pragma unroll
  for (int m = 0; m < 2; m++)
#pragma unroll
    for (int i = 0; i < 4; i++)
      qf[m][i] = *(const short8*)(Qp + (m * 16 + r16) * HD + i * 32 + q4 * 8);

  f32x4 zero = {0.f, 0.f, 0.f, 0.f};
  f32x4 o[2][8];
  float mrow[2][4], Lp[2][4];
#pragma unroll
  for (int m = 0; m < 2; m++) {
#pragma unroll
    for (int nb = 0; nb < 8; nb++) o[m][nb] = zero;
#pragma unroll
    for (int j = 0; j < 4; j++) { mrow[m][j] = -1e30f; Lp[m][j] = 0.f; }
  }

  auto stageK = [&](int kv0, int buf) {
#pragma unroll
    for (int j = 0; j < 4; ++j) {
      int cw = w * 4 + j;
      int row = cw * 4 + (lane >> 4);
      int cb = lane & 15;
      gload_lds16(Kp + (size_t)(kv0 + row) * HD + ((cb ^ (row & 7)) * 8), &lK[buf][cw * 512]);
    }
  };
  auto stageV = [&](int kv0, int buf) {
#pragma unroll
    for (int j = 0; j < 4; ++j) {
      int cw = w * 4 + j;
      int row = cw * 8 + (lane >> 3);
      int db = lane & 7;
      gload_lds16(Vp + (size_t)row * T_SEQ + kv0 + ((db ^ (row & 7)) * 8), &lV[buf][cw * 512]);
    }
  };

  const int ntiles = 2 * qt + 2;
  const int ntw = (Q0 + w * 32 + 95) >> 6;

  stageK(0, 0);
  stageV(0, 0);
  __syncthreads();
  int cur = 0;

  for (int t = 0; t < ntiles; ++t) {
    int kv0 = t * 64;
    if (t + 1 < ntiles) { stageK(kv0 + 64, cur ^ 1); stageV(kv0 + 64, cur ^ 1); }
    if (t < ntw) {
      f32x4 s[2][4];
      __builtin_amdgcn_s_setprio(1);
#pragma unroll
      for (int nt = 0; nt < 4; nt++) {
        f32x4 a0 = zero, a1 = zero;
        int krow = nt * 16 + r16;
#pragma unroll
        for (int i = 0; i < 4; i++) {
          short8 kf =
              *(const short8*)(&lK[cur][krow * 128 + ((q4 * 8 + i * 32) ^ ((krow & 7) << 3))]);
          a0 = __builtin_amdgcn_mfma_f32_16x16x32_bf16(qf[0][i], kf, a0, 0, 0, 0);
          a1 = __builtin_amdgcn_mfma_f32_16x16x32_bf16(qf[1][i], kf, a1, 0, 0, 0);
        }
        s[0][nt] = a0;
        s[1][nt] = a1;
      }
      __builtin_amdgcn_s_setprio(0);
      if (kv0 + 63 > Q0 + w * 32) {
#pragma unroll
        for (int m = 0; m < 2; m++)
#pragma unroll
          for (int nt = 0; nt < 4; nt++)
#pragma unroll
            for (int j = 0; j < 4; j++) {
              int col = kv0 + nt * 16 + r16;
              int row = Q0 + w * 32 + m * 16 + q4 * 4 + j;
              if (col > row) s[m][nt][j] = -1e30f;
            }
      }
      float pm[2][4];
#pragma unroll
      for (int m = 0; m < 2; m++)
#pragma unroll
        for (int j = 0; j < 4; j++)
          pm[m][j] = fmaxf(fmaxf(s[m][0][j], s[m][1][j]), fmaxf(s[m][2][j], s[m][3][j]));
#pragma unroll
      for (int d = 1; d < 16; d <<= 1)
#pragma unroll
        for (int m = 0; m < 2; m++)
#pragma unroll
          for (int j = 0; j < 4; j++) pm[m][j] = fmaxf(pm[m][j], __shfl_xor(pm[m][j], d));
      float dmax = -1e30f;
#pragma unroll
      for (int m = 0; m < 2; m++)
#pragma unroll
        for (int j = 0; j < 4; j++) dmax = fmaxf(dmax, pm[m][j] - mrow[m][j]);
      if (!__all(dmax <= 8.0f)) {
#pragma unroll
        for (int m = 0; m < 2; m++)
#pragma unroll
          for (int j = 0; j < 4; j++) {
            float mn = fmaxf(mrow[m][j], pm[m][j]);
            float al = __expf(mrow[m][j] - mn);
            mrow[m][j] = mn;
            Lp[m][j] *= al;
#pragma unroll
            for (int nb = 0; nb < 8; nb++) o[m][nb][j] *= al;
          }
      }
#pragma unroll
      for (int m = 0; m < 2; m++)
#pragma unroll
        for (int nt = 0; nt < 4; nt++)
#pragma unroll
          for (int j = 0; j < 4; j++) {
            float p = __expf(s[m][nt][j] - mrow[m][j]);
            Lp[m][j] += p;
            int prow = m * 16 + q4 * 4 + j;
            pl[w][prow * 64 + ((nt * 16 + r16) ^ (swzP(prow) << 3))] = f2bf(p);
          }
      __builtin_amdgcn_s_setprio(1);
#pragma unroll
      for (int ks = 0; ks < 2; ks++) {
        int t0 = ks * 32 + q4 * 8;
        int prow0 = r16, prow1 = 16 + r16;
        short8 pf0 = *(const short8*)(&pl[w][prow0 * 64 + (t0 ^ (swzP(prow0) << 3))]);
        short8 pf1 = *(const short8*)(&pl[w][prow1 * 64 + (t0 ^ (swzP(prow1) << 3))]);
#pragma unroll
        for (int nb = 0; nb < 8; nb++) {
          int vrow = nb * 16 + r16;
          short8 vf = *(const short8*)(&lV[cur][vrow * 64 + (t0 ^ ((vrow & 7) << 3))]);
          o[0][nb] = __builtin_amdgcn_mfma_f32_16x16x32_bf16(pf0, vf, o[0][nb], 0, 0, 0);
          o[1][nb] = __builtin_amdgcn_mfma_f32_16x16x32_bf16(pf1, vf, o[1][nb], 0, 0, 0);
        }
      }
      __builtin_amdgcn_s_setprio(0);
    }
    __syncthreads();
    cur ^= 1;
  }

  float linv[2][4];
#pragma unroll
  for (int m = 0; m < 2; m++)
#pragma unroll
    for (int j = 0; j < 4; j++) {
      float v = Lp[m][j];
#pragma unroll
      for (int d = 1; d < 16; d <<= 1) v += __shfl_xor(v, d);
      linv[m][j] = 1.f / v;
    }
#pragma unroll
  for (int m = 0; m < 2; m++)
#pragma unroll
    for (int nb = 0; nb < 8; nb++)
#pragma unroll
      for (int j = 0; j < 4; j++) {
        size_t row = (size_t)Q0 + w * 32 + m * 16 + q4 * 4 + j;
        Y[((size_t)(b * T_SEQ) + row) * (NH * HD) + h * HD + nb * 16 + r16] =
            f2bf(o[m][nb][j] * linv[m][j]);
      }
}

extern "C" void kernel_launch(void* const* d_in, const int* in_sizes, int n_in,
                              void* d_out, int out_size, void* d_ws, size_t ws_size,
                              hipStream_t stream) {
  const float* x = (const float*)d_in[0];
  const float* cosp = (const float*)d_in[1];
  const float* sinp = (const float*)d_in[2];
  const float* Wq = (const float*)d_in[3];
  const float* Wk = (const float*)d_in[4];
  const float* Wv = (const float*)d_in[5];
  const float* Wo = (const float*)d_in[6];
  float* out = (float*)d_out;

  char* ws = (char*)d_ws;
  size_t off = 0;
  auto alloc = [&](size_t bytes) { void* p = ws + off; off += bytes; return p; };
  const size_t BT = (size_t)B_SZ * T_SEQ;  // 8192
  unsigned short* xb = (unsigned short*)alloc(BT * C_DIM * 2);                 // 32MB
  unsigned short* WqkvT = (unsigned short*)alloc((size_t)3072 * 2048 * 2);     // 12.6MB
  unsigned short* WoT = (unsigned short*)alloc((size_t)2048 * 2048 * 2);       // 8.4MB
  unsigned short* qkv = (unsigned short*)alloc(BT * 3072 * 2);                 // 48MB
  unsigned short* Kb = (unsigned short*)alloc(BT * 512 * 2);                   // 8MB
  unsigned short* Vb = (unsigned short*)alloc(BT * 512 * 2);                   // 8MB
  unsigned short* Qb = xb;   // alias: xb dead after qkv GEMM
  unsigned short* Yb = qkv;  // alias: qkv dead after ropenorm/vtrans

  dim3 tb(32, 8);
  cast_x<<<16384, 256, 0, stream>>>(x, xb, (int)(BT * C_DIM / 4));
  wtrans<<<dim3(64, 64), tb, 0, stream>>>(Wq, WqkvT, 2048, 2048);
  wtrans<<<dim3(64, 16), tb, 0, stream>>>(Wk, WqkvT + (size_t)2048 * 2048, 2048, 512);
  wtrans<<<dim3(64, 16), tb, 0, stream>>>(Wv, WqkvT + (size_t)2560 * 2048, 2048, 512);
  wtrans<<<dim3(64, 64), tb, 0, stream>>>(Wo, WoT, 2048, 2048);

  // qkv GEMM: M=8192, N=3072, K=2048 -> 32 x 12 = 384 blocks
  gemm256<unsigned short><<<384, 512, 0, stream>>>(xb, WqkvT, qkv, 3072, 2048, 32);

  ropenorm<NH><<<(B_SZ * T_SEQ * NH) / 4, 256, 0, stream>>>(qkv, 0, cosp, sinp, Qb,
                                                            0.08838834764831845f);  // 1/sqrt(128)
  ropenorm<NKV><<<(B_SZ * T_SEQ * NKV) / 4, 256, 0, stream>>>(qkv, 2048, cosp, sinp, Kb, 1.0f);
  vtrans<<<dim3(64, 4, 16), tb, 0, stream>>>(qkv, Vb);

  attn<<<dim3(1024), 256, 0, stream>>>(Qb, Kb, Vb, Yb);

  // out-proj GEMM: M=8192, N=2048, K=2048 -> 32 x 8 = 256 blocks
  gemm256<float><<<256, 512, 0, stream>>>(Yb, WoT, out, 2048, 2048, 32);
}

// Round 6
// 426.323 us; speedup vs baseline: 2.7617x; 1.0194x over previous
//
#include <hip/hip_runtime.h>
#include <hip/hip_bf16.h>

typedef __attribute__((ext_vector_type(8))) short short8;
typedef __attribute__((ext_vector_type(4))) float f32x4;

#define B_SZ 4
#define T_SEQ 2048
#define C_DIM 2048
#define NH 16
#define NKV 4
#define HD 128

#define MFMA16 __builtin_amdgcn_mfma_f32_16x16x32_bf16

__device__ __forceinline__ unsigned short f2bf(float f) {
  union { __hip_bfloat16 h; unsigned short u; } v;
  v.h = __float2bfloat16(f);
  return v.u;
}
__device__ __forceinline__ float bf2f(unsigned short u) {
  union { unsigned short u; __hip_bfloat16 h; } v;
  v.u = u;
  return __bfloat162float(v.h);
}

__device__ __forceinline__ void gload_lds16(const unsigned short* g, unsigned short* l) {
  __builtin_amdgcn_global_load_lds(
      (const __attribute__((address_space(1))) unsigned int*)g,
      (__attribute__((address_space(3))) unsigned int*)l, 16, 0, 0);
}

// ---------------- cast x (fp32 -> bf16), vectorized ----------------
__global__ void cast_x(const float* __restrict__ x, unsigned short* __restrict__ xb, int n4) {
  int i = blockIdx.x * blockDim.x + threadIdx.x;
  if (i < n4) {
    float4 f = ((const float4*)x)[i];
    ushort4 u = make_ushort4(f2bf(f.x), f2bf(f.y), f2bf(f.z), f2bf(f.w));
    ((ushort4*)xb)[i] = u;
  }
}

// ---------------- all weight transposes in ONE launch ----------------
// y<64: Wq -> WqkvT[0..2048)        y in [64,80): Wk -> WqkvT[2048..2560)
// y in [80,96): Wv -> WqkvT[2560..3072)   y>=96: Wo -> WoT
__global__ void wtransAll(const float* __restrict__ Wq, const float* __restrict__ Wk,
                          const float* __restrict__ Wv, const float* __restrict__ Wo,
                          unsigned short* __restrict__ WqkvT, unsigned short* __restrict__ WoT) {
  __shared__ float tile[32][33];
  int y = blockIdx.y;
  const float* W;
  unsigned short* Wt;
  int N, n0;
  if (y < 64) { W = Wq; Wt = WqkvT; N = 2048; n0 = y * 32; }
  else if (y < 80) { W = Wk; Wt = WqkvT + (size_t)2048 * 2048; N = 512; n0 = (y - 64) * 32; }
  else if (y < 96) { W = Wv; Wt = WqkvT + (size_t)2560 * 2048; N = 512; n0 = (y - 80) * 32; }
  else { W = Wo; Wt = WoT; N = 2048; n0 = (y - 96) * 32; }
  int k0 = blockIdx.x * 32;
  int tx = threadIdx.x, ty = threadIdx.y;
#pragma unroll
  for (int i = 0; i < 4; i++)
    tile[ty + i * 8][tx] = W[(size_t)(k0 + ty + i * 8) * N + n0 + tx];
  __syncthreads();
#pragma unroll
  for (int i = 0; i < 4; i++)
    Wt[(size_t)(n0 + ty + i * 8) * 2048 + k0 + tx] = f2bf(tile[tx][ty + i * 8]);
}

// ---------------- V transpose: qkv (B,T,3072) cols [2560+kvh*128+d] -> Vt (B,KVH,D,T) ----------------
__global__ void vtrans(const unsigned short* __restrict__ qkv, unsigned short* __restrict__ Vt) {
  __shared__ unsigned short tile[32][34];
  int t0 = blockIdx.x * 32, d0 = blockIdx.y * 32;
  int b = blockIdx.z >> 2, kvh = blockIdx.z & 3;
  int tx = threadIdx.x, ty = threadIdx.y;
#pragma unroll
  for (int i = 0; i < 4; i++)
    tile[ty + i * 8][tx] =
        qkv[(size_t)(b * T_SEQ + t0 + ty + i * 8) * 3072 + 2560 + kvh * HD + d0 + tx];
  __syncthreads();
#pragma unroll
  for (int i = 0; i < 4; i++)
    Vt[((size_t)(b * NKV + kvh) * HD + d0 + ty + i * 8) * T_SEQ + t0 + tx] = tile[tx][ty + i * 8];
}

// ---------------- 128x256 2-phase counted-vmcnt GEMM (for qkv: 768 blocks = 3.0 rounds) ----
// 512 thr = 8 waves (2m x 4n); per-wave C = 64x64 (4x4 frags). LDS 96KB:
// buf[2] x {A(128x64), B0(128x64), B1(128x64)}. B staged 1-ahead, A staged 2-ahead;
// steady-state vmcnt(2) (A of t+2 in flight), vmcnt(0) only at final drain.
template <typename OutT>
__global__ __launch_bounds__(512, 2) void gemm128(const unsigned short* __restrict__ A,
                                                  const unsigned short* __restrict__ Bt,
                                                  OutT* __restrict__ Cc, int N, int K, int GX) {
  __shared__ alignas(16) unsigned short lds[2][3][128 * 64];  // 0=A, 1=B0, 2=B1
  const int tid = threadIdx.x, lane = tid & 63, wid = tid >> 6;
  const int wave_m = wid >> 2, wave_n = wid & 3;
  const int r16 = lane & 15, q4 = lane >> 4;
  const int sw = r16 & 7;

  int nwg = gridDim.x, orig = blockIdx.x;
  int qq = nwg >> 3, rr = nwg & 7;
  int xcd = orig & 7, loc = orig >> 3;
  int wg = (xcd < rr ? xcd * (qq + 1) : rr * (qq + 1) + (xcd - rr) * qq) + loc;
  int bx = wg % GX, by = wg / GX;
  const size_t row0 = (size_t)bx * 128, col0 = (size_t)by * 256;

  const unsigned short* Ab = A + row0 * K;
  const unsigned short* Bb0 = Bt + col0 * K;
  const unsigned short* Bb1 = Bt + (col0 + 128) * K;

  const int srow = lane >> 3, spb = lane & 7;
  auto stage = [&](const unsigned short* base, int buf, int slot, int k0) {
#pragma unroll
    for (int j = 0; j < 2; ++j) {
      int cw = j * 8 + wid;
      int row = cw * 8 + srow;
      gload_lds16(base + (size_t)row * K + k0 + ((spb ^ srow) * 8), &lds[buf][slot][cw * 512]);
    }
  };

  f32x4 acc[4][4];
  f32x4 zero = {0.f, 0.f, 0.f, 0.f};
#pragma unroll
  for (int m = 0; m < 4; m++)
#pragma unroll
    for (int n = 0; n < 4; n++) acc[m][n] = zero;

  const int NT = K / 64;
  // prologue: tile0 {A,B0,B1}, tile1 {A}
  stage(Ab, 0, 0, 0);
  stage(Bb0, 0, 1, 0);
  stage(Bb1, 0, 2, 0);
  stage(Ab, 1, 0, 64);
  asm volatile("s_waitcnt vmcnt(2)" ::: "memory");
  __builtin_amdgcn_s_barrier();

  short8 af[4][2], b01[2][2], b23[2][2];
  const int bslot = 1 + (wave_n >> 1);
  const int bro = (wave_n & 1) * 64;

  int cur = 0;
#pragma unroll 1
  for (int t = 0; t < NT; ++t) {
    const unsigned short* Ah = &lds[cur][0][0];
    const unsigned short* Bh = &lds[cur][bslot][0];
    const int k1 = t * 64 + 64, k2 = t * 64 + 128;
    // ---- P0: read a0-3 + b01; stage t+1.B0; MFMA (n0-1) ----
#pragma unroll
    for (int mf = 0; mf < 4; mf++)
#pragma unroll
      for (int kk = 0; kk < 2; kk++)
        af[mf][kk] =
            *(const short8*)(Ah + (wave_m * 64 + mf * 16 + r16) * 64 + (((kk * 4 + q4) ^ sw) * 8));
#pragma unroll
    for (int nf = 0; nf < 2; nf++)
#pragma unroll
      for (int kk = 0; kk < 2; kk++)
        b01[nf][kk] =
            *(const short8*)(Bh + (bro + nf * 16 + r16) * 64 + (((kk * 4 + q4) ^ sw) * 8));
    if (t + 1 < NT) stage(Bb0, cur ^ 1, 1, k1);
    __builtin_amdgcn_s_barrier();
    asm volatile("s_waitcnt lgkmcnt(0)" ::: "memory");
    __builtin_amdgcn_s_setprio(1);
#pragma unroll
    for (int mf = 0; mf < 4; mf++)
#pragma unroll
      for (int nf = 0; nf < 2; nf++)
#pragma unroll
        for (int kk = 0; kk < 2; kk++)
          acc[mf][nf] = MFMA16(af[mf][kk], b01[nf][kk], acc[mf][nf], 0, 0, 0);
    __builtin_amdgcn_s_setprio(0);
    __builtin_amdgcn_s_barrier();
    // ---- P1: read b23; stage t+1.B1 + t+2.A; MFMA (n2-3); counted vmcnt ----
#pragma unroll
    for (int nf = 0; nf < 2; nf++)
#pragma unroll
      for (int kk = 0; kk < 2; kk++)
        b23[nf][kk] =
            *(const short8*)(Bh + (bro + (nf + 2) * 16 + r16) * 64 + (((kk * 4 + q4) ^ sw) * 8));
    if (t + 1 < NT) stage(Bb1, cur ^ 1, 2, k1);
    if (t + 2 < NT) stage(Ab, cur, 0, k2);  // A slot of buf cur free after P0
    __builtin_amdgcn_s_barrier();
    asm volatile("s_waitcnt lgkmcnt(0)" ::: "memory");
    __builtin_amdgcn_s_setprio(1);
#pragma unroll
    for (int mf = 0; mf < 4; mf++)
#pragma unroll
      for (int nf = 0; nf < 2; nf++)
#pragma unroll
        for (int kk = 0; kk < 2; kk++)
          acc[mf][nf + 2] = MFMA16(af[mf][kk], b23[nf][kk], acc[mf][nf + 2], 0, 0, 0);
    __builtin_amdgcn_s_setprio(0);
    if (t + 2 < NT)
      asm volatile("s_waitcnt vmcnt(2)" ::: "memory");  // t+1 resident; t+2.A in flight
    else if (t + 1 < NT)
      asm volatile("s_waitcnt vmcnt(0)" ::: "memory");  // final drain
    __builtin_amdgcn_s_barrier();
    cur ^= 1;
  }

#pragma unroll
  for (int mf = 0; mf < 4; mf++)
#pragma unroll
    for (int nf = 0; nf < 4; nf++) {
      size_t rbase = row0 + wave_m * 64 + mf * 16 + q4 * 4;
      size_t cc = col0 + wave_n * 64 + nf * 16 + r16;
#pragma unroll
      for (int jj = 0; jj < 4; jj++) {
        if constexpr (sizeof(OutT) == 2)
          Cc[(rbase + jj) * (size_t)N + cc] = f2bf(acc[mf][nf][jj]);
        else
          Cc[(rbase + jj) * (size_t)N + cc] = acc[mf][nf][jj];
      }
    }
}

// ---------------- 256x256 8-phase GEMM (for out-proj: 256 blocks = 1.0 round) ----------------
template <typename OutT>
__global__ __launch_bounds__(512, 2) void gemm256(const unsigned short* __restrict__ A,
                                                  const unsigned short* __restrict__ Bt,
                                                  OutT* __restrict__ Cc, int N, int K, int GX) {
  __shared__ alignas(16) unsigned short lds[2][4][128 * 64];
  const int tid = threadIdx.x, lane = tid & 63, wid = tid >> 6;
  const int wave_m = wid >> 2, wave_n = wid & 3;
  const int r16 = lane & 15, q4 = lane >> 4;
  const int sw = r16 & 7;

  int nwg = gridDim.x, orig = blockIdx.x;
  int qq = nwg >> 3, rr = nwg & 7;
  int xcd = orig & 7, loc = orig >> 3;
  int wg = (xcd < rr ? xcd * (qq + 1) : rr * (qq + 1) + (xcd - rr) * qq) + loc;
  int bx = wg % GX, by = wg / GX;
  const size_t row0 = (size_t)bx * 256, col0 = (size_t)by * 256;

  const unsigned short* Ab0 = A + row0 * K;
  const unsigned short* Ab1 = A + (row0 + 128) * K;
  const unsigned short* Bb0 = Bt + col0 * K;
  const unsigned short* Bb1 = Bt + (col0 + 128) * K;

  const int srow = lane >> 3, spb = lane & 7;
  auto stage = [&](const unsigned short* base, int buf, int slot, int k0) {
#pragma unroll
    for (int j = 0; j < 2; ++j) {
      int cw = j * 8 + wid;
      int row = cw * 8 + srow;
      gload_lds16(base + (size_t)row * K + k0 + ((spb ^ srow) * 8), &lds[buf][slot][cw * 512]);
    }
  };

  f32x4 acc[8][4];
  f32x4 zero = {0.f, 0.f, 0.f, 0.f};
#pragma unroll
  for (int m = 0; m < 8; m++)
#pragma unroll
    for (int n = 0; n < 4; n++) acc[m][n] = zero;

  const int NT = K / 64;
  stage(Ab0, 0, 0, 0);
  stage(Ab1, 0, 1, 0);
  stage(Bb0, 0, 2, 0);
  stage(Bb1, 0, 3, 0);
  stage(Ab0, 1, 0, 64);
  stage(Ab1, 1, 1, 64);
  asm volatile("s_waitcnt vmcnt(4)" ::: "memory");
  __builtin_amdgcn_s_barrier();

  short8 af[4][2], b01[2][2], b23[2][2];
  const int bslot = 2 + (wave_n >> 1);
  const int bro = (wave_n & 1) * 64;

  int cur = 0;
#pragma unroll 1
  for (int t = 0; t < NT; ++t) {
    const unsigned short* Ah = &lds[cur][wave_m][0];
    const unsigned short* Bh = &lds[cur][bslot][0];
    const int k1 = t * 64 + 64, k2 = t * 64 + 128;
#pragma unroll
    for (int mf = 0; mf < 4; mf++)
#pragma unroll
      for (int kk = 0; kk < 2; kk++)
        af[mf][kk] = *(const short8*)(Ah + (mf * 16 + r16) * 64 + (((kk * 4 + q4) ^ sw) * 8));
#pragma unroll
    for (int nf = 0; nf < 2; nf++)
#pragma unroll
      for (int kk = 0; kk < 2; kk++)
        b01[nf][kk] =
            *(const short8*)(Bh + (bro + nf * 16 + r16) * 64 + (((kk * 4 + q4) ^ sw) * 8));
    if (t + 1 < NT) stage(Bb0, cur ^ 1, 2, k1);
    __builtin_amdgcn_s_barrier();
    asm volatile("s_waitcnt lgkmcnt(0)" ::: "memory");
    __builtin_amdgcn_s_setprio(1);
#pragma unroll
    for (int mf = 0; mf < 4; mf++)
#pragma unroll
      for (int nf = 0; nf < 2; nf++)
#pragma unroll
        for (int kk = 0; kk < 2; kk++)
          acc[mf][nf] = MFMA16(af[mf][kk], b01[nf][kk], acc[mf][nf], 0, 0, 0);
    __builtin_amdgcn_s_setprio(0);
    __builtin_amdgcn_s_barrier();
#pragma unroll
    for (int nf = 0; nf < 2; nf++)
#pragma unroll
      for (int kk = 0; kk < 2; kk++)
        b23[nf][kk] =
            *(const short8*)(Bh + (bro + (nf + 2) * 16 + r16) * 64 + (((kk * 4 + q4) ^ sw) * 8));
    if (t + 1 < NT) stage(Bb1, cur ^ 1, 3, k1);
    __builtin_amdgcn_s_barrier();
    asm volatile("s_waitcnt lgkmcnt(0)" ::: "memory");
    __builtin_amdgcn_s_setprio(1);
#pragma unroll
    for (int mf = 0; mf < 4; mf++)
#pragma unroll
      for (int nf = 0; nf < 2; nf++)
#pragma unroll
        for (int kk = 0; kk < 2; kk++)
          acc[mf][nf + 2] = MFMA16(af[mf][kk], b23[nf][kk], acc[mf][nf + 2], 0, 0, 0);
    __builtin_amdgcn_s_setprio(0);
    __builtin_amdgcn_s_barrier();
#pragma unroll
    for (int mf = 0; mf < 4; mf++)
#pragma unroll
      for (int kk = 0; kk < 2; kk++)
        af[mf][kk] =
            *(const short8*)(Ah + ((mf + 4) * 16 + r16) * 64 + (((kk * 4 + q4) ^ sw) * 8));
    __builtin_amdgcn_s_barrier();
    asm volatile("s_waitcnt lgkmcnt(0)" ::: "memory");
    __builtin_amdgcn_s_setprio(1);
#pragma unroll
    for (int mf = 0; mf < 4; mf++)
#pragma unroll
      for (int nf = 0; nf < 2; nf++)
#pragma unroll
        for (int kk = 0; kk < 2; kk++)
          acc[mf + 4][nf] = MFMA16(af[mf][kk], b01[nf][kk], acc[mf + 4][nf], 0, 0, 0);
    __builtin_amdgcn_s_setprio(0);
    __builtin_amdgcn_s_barrier();
    if (t + 2 < NT) {
      stage(Ab0, cur, 0, k2);
      stage(Ab1, cur, 1, k2);
    }
    __builtin_amdgcn_s_barrier();
    __builtin_amdgcn_s_setprio(1);
#pragma unroll
    for (int mf = 0; mf < 4; mf++)
#pragma unroll
      for (int nf = 0; nf < 2; nf++)
#pragma unroll
        for (int kk = 0; kk < 2; kk++)
          acc[mf + 4][nf + 2] = MFMA16(af[mf][kk], b23[nf][kk], acc[mf + 4][nf + 2], 0, 0, 0);
    __builtin_amdgcn_s_setprio(0);
    if (t + 1 < NT) {
      if (t + 2 < NT)
        asm volatile("s_waitcnt vmcnt(4)" ::: "memory");
      else
        asm volatile("s_waitcnt vmcnt(0)" ::: "memory");
    }
    __builtin_amdgcn_s_barrier();
    cur ^= 1;
  }

#pragma unroll
  for (int mf = 0; mf < 8; mf++)
#pragma unroll
    for (int nf = 0; nf < 4; nf++) {
      size_t rbase = row0 + wave_m * 128 + mf * 16 + q4 * 4;
      size_t cc = col0 + wave_n * 64 + nf * 16 + r16;
#pragma unroll
      for (int jj = 0; jj < 4; jj++) {
        if constexpr (sizeof(OutT) == 2)
          Cc[(rbase + jj) * (size_t)N + cc] = f2bf(acc[mf][nf][jj]);
        else
          Cc[(rbase + jj) * (size_t)N + cc] = acc[mf][nf][jj];
      }
    }
}

// ---------------- fused RoPE + RMSNorm, Q and K in ONE launch ----------------
// per (b,t): heads 0..15 = Q (colbase h*128, scaled), 16..19 = K head h-16
__global__ void ropeAll(const unsigned short* __restrict__ qkv, const float* __restrict__ cosp,
                        const float* __restrict__ sinp, unsigned short* __restrict__ Qb,
                        unsigned short* __restrict__ Kb) {
  int gid = blockIdx.x * 4 + (threadIdx.x >> 6);
  int lane = threadIdx.x & 63;
  int hh = gid % 20;
  int bt = gid / 20;
  int t = bt % T_SEQ, b = bt / T_SEQ;
  int colbase;
  unsigned short* dst;
  float outscale;
  if (hh < 16) {
    colbase = hh * HD;
    dst = Qb + ((size_t)(b * NH + hh) * T_SEQ + t) * HD;
    outscale = 0.08838834764831845f;  // 1/sqrt(128)
  } else {
    int h2 = hh - 16;
    colbase = 2048 + h2 * HD;
    dst = Kb + ((size_t)(b * NKV + h2) * T_SEQ + t) * HD;
    outscale = 1.0f;
  }
  const unsigned short* src = qkv + (size_t)(b * T_SEQ + t) * 3072 + colbase;
  float x1 = bf2f(src[lane]), x2 = bf2f(src[64 + lane]);
  float c = cosp[t * 64 + lane], s = sinp[t * 64 + lane];
  float y1 = x1 * c + x2 * s;
  float y2 = x2 * c - x1 * s;
  float ss = y1 * y1 + y2 * y2;
#pragma unroll
  for (int d = 1; d < 64; d <<= 1) ss += __shfl_xor(ss, d);
  float r = rsqrtf(ss * (1.f / 128.f) + 1e-6f) * outscale;
  dst[lane] = f2bf(y1 * r);
  dst[64 + lane] = f2bf(y2 * r);
}

// P-tile row swizzle
__device__ __forceinline__ int swzP(int row) {
  return (row & 7) ^ (((row >> 3) & 1) << 1);
}

// ---------------- flash attention (unchanged / frozen) ----------------
__global__ __launch_bounds__(256, 2) void attn(const unsigned short* __restrict__ Qn,
                                               const unsigned short* __restrict__ Kn,
                                               const unsigned short* __restrict__ Vt,
                                               unsigned short* __restrict__ Y) {
  __shared__ alignas(16) unsigned short lK[2][64 * 128];
  __shared__ alignas(16) unsigned short lV[2][128 * 64];
  __shared__ alignas(16) unsigned short pl[4][32 * 64];

  int lin = blockIdx.x;
  int low3 = lin & 7, rest = lin >> 3;
  int chi = rest >> 6, idx = rest & 63;
  int c = (chi << 3) | low3;
  int b = c >> 2, kvh = c & 3;
  int h = kvh * 4 + (idx >> 4);
  int qt = 15 - (idx & 15);
  int Q0 = qt * 128;

  int lane = threadIdx.x & 63, w = threadIdx.x >> 6;
  const int r16 = lane & 15, q4 = lane >> 4;
  const unsigned short* Qp = Qn + ((size_t)(b * NH + h) * T_SEQ + Q0 + w * 32) * HD;
  const unsigned short* Kp = Kn + (size_t)(b * NKV + kvh) * T_SEQ * HD;
  const unsigned short* Vp = Vt + (size_t)(b * NKV + kvh) * HD * T_SEQ;

  short8 qf[2][4];
#pragma unroll
  for (int m = 0; m < 2; m++)
#pragma unroll
    for (int i = 0; i < 4; i++)
      qf[m][i] = *(const short8*)(Qp + (m * 16 + r16) * HD + i * 32 + q4 * 8);

  f32x4 zero = {0.f, 0.f, 0.f, 0.f};
  f32x4 o[2][8];
  float mrow[2][4], Lp[2][4];
#pragma unroll
  for (int m = 0; m < 2; m++) {
#pragma unroll
    for (int nb = 0; nb < 8; nb++) o[m][nb] = zero;
#pragma unroll
    for (int j = 0; j < 4; j++) { mrow[m][j] = -1e30f; Lp[m][j] = 0.f; }
  }

  auto stageK = [&](int kv0, int buf) {
#pragma unroll
    for (int j = 0; j < 4; ++j) {
      int cw = w * 4 + j;
      int row = cw * 4 + (lane >> 4);
      int cb = lane & 15;
      gload_lds16(Kp + (size_t)(kv0 + row) * HD + ((cb ^ (row & 7)) * 8), &lK[buf][cw * 512]);
    }
  };
  auto stageV = [&](int kv0, int buf) {
#pragma unroll
    for (int j = 0; j < 4; ++j) {
      int cw = w * 4 + j;
      int row = cw * 8 + (lane >> 3);
      int db = lane & 7;
      gload_lds16(Vp + (size_t)row * T_SEQ + kv0 + ((db ^ (row & 7)) * 8), &lV[buf][cw * 512]);
    }
  };

  const int ntiles = 2 * qt + 2;
  const int ntw = (Q0 + w * 32 + 95) >> 6;

  stageK(0, 0);
  stageV(0, 0);
  __syncthreads();
  int cur = 0;

  for (int t = 0; t < ntiles; ++t) {
    int kv0 = t * 64;
    if (t + 1 < ntiles) { stageK(kv0 + 64, cur ^ 1); stageV(kv0 + 64, cur ^ 1); }
    if (t < ntw) {
      f32x4 s[2][4];
      __builtin_amdgcn_s_setprio(1);
#pragma unroll
      for (int nt = 0; nt < 4; nt++) {
        f32x4 a0 = zero, a1 = zero;
        int krow = nt * 16 + r16;
#pragma unroll
        for (int i = 0; i < 4; i++) {
          short8 kf =
              *(const short8*)(&lK[cur][krow * 128 + ((q4 * 8 + i * 32) ^ ((krow & 7) << 3))]);
          a0 = __builtin_amdgcn_mfma_f32_16x16x32_bf16(qf[0][i], kf, a0, 0, 0, 0);
          a1 = __builtin_amdgcn_mfma_f32_16x16x32_bf16(qf[1][i], kf, a1, 0, 0, 0);
        }
        s[0][nt] = a0;
        s[1][nt] = a1;
      }
      __builtin_amdgcn_s_setprio(0);
      if (kv0 + 63 > Q0 + w * 32) {
#pragma unroll
        for (int m = 0; m < 2; m++)
#pragma unroll
          for (int nt = 0; nt < 4; nt++)
#pragma unroll
            for (int j = 0; j < 4; j++) {
              int col = kv0 + nt * 16 + r16;
              int row = Q0 + w * 32 + m * 16 + q4 * 4 + j;
              if (col > row) s[m][nt][j] = -1e30f;
            }
      }
      float pm[2][4];
#pragma unroll
      for (int m = 0; m < 2; m++)
#pragma unroll
        for (int j = 0; j < 4; j++)
          pm[m][j] = fmaxf(fmaxf(s[m][0][j], s[m][1][j]), fmaxf(s[m][2][j], s[m][3][j]));
#pragma unroll
      for (int d = 1; d < 16; d <<= 1)
#pragma unroll
        for (int m = 0; m < 2; m++)
#pragma unroll
          for (int j = 0; j < 4; j++) pm[m][j] = fmaxf(pm[m][j], __shfl_xor(pm[m][j], d));
      float dmax = -1e30f;
#pragma unroll
      for (int m = 0; m < 2; m++)
#pragma unroll
        for (int j = 0; j < 4; j++) dmax = fmaxf(dmax, pm[m][j] - mrow[m][j]);
      if (!__all(dmax <= 8.0f)) {
#pragma unroll
        for (int m = 0; m < 2; m++)
#pragma unroll
          for (int j = 0; j < 4; j++) {
            float mn = fmaxf(mrow[m][j], pm[m][j]);
            float al = __expf(mrow[m][j] - mn);
            mrow[m][j] = mn;
            Lp[m][j] *= al;
#pragma unroll
            for (int nb = 0; nb < 8; nb++) o[m][nb][j] *= al;
          }
      }
#pragma unroll
      for (int m = 0; m < 2; m++)
#pragma unroll
        for (int nt = 0; nt < 4; nt++)
#pragma unroll
          for (int j = 0; j < 4; j++) {
            float p = __expf(s[m][nt][j] - mrow[m][j]);
            Lp[m][j] += p;
            int prow = m * 16 + q4 * 4 + j;
            pl[w][prow * 64 + ((nt * 16 + r16) ^ (swzP(prow) << 3))] = f2bf(p);
          }
      __builtin_amdgcn_s_setprio(1);
#pragma unroll
      for (int ks = 0; ks < 2; ks++) {
        int t0 = ks * 32 + q4 * 8;
        int prow0 = r16, prow1 = 16 + r16;
        short8 pf0 = *(const short8*)(&pl[w][prow0 * 64 + (t0 ^ (swzP(prow0) << 3))]);
        short8 pf1 = *(const short8*)(&pl[w][prow1 * 64 + (t0 ^ (swzP(prow1) << 3))]);
#pragma unroll
        for (int nb = 0; nb < 8; nb++) {
          int vrow = nb * 16 + r16;
          short8 vf = *(const short8*)(&lV[cur][vrow * 64 + (t0 ^ ((vrow & 7) << 3))]);
          o[0][nb] = __builtin_amdgcn_mfma_f32_16x16x32_bf16(pf0, vf, o[0][nb], 0, 0, 0);
          o[1][nb] = __builtin_amdgcn_mfma_f32_16x16x32_bf16(pf1, vf, o[1][nb], 0, 0, 0);
        }
      }
      __builtin_amdgcn_s_setprio(0);
    }
    __syncthreads();
    cur ^= 1;
  }

  float linv[2][4];
#pragma unroll
  for (int m = 0; m < 2; m++)
#pragma unroll
    for (int j = 0; j < 4; j++) {
      float v = Lp[m][j];
#pragma unroll
      for (int d = 1; d < 16; d <<= 1) v += __shfl_xor(v, d);
      linv[m][j] = 1.f / v;
    }
#pragma unroll
  for (int m = 0; m < 2; m++)
#pragma unroll
    for (int nb = 0; nb < 8; nb++)
#pragma unroll
      for (int j = 0; j < 4; j++) {
        size_t row = (size_t)Q0 + w * 32 + m * 16 + q4 * 4 + j;
        Y[((size_t)(b * T_SEQ) + row) * (NH * HD) + h * HD + nb * 16 + r16] =
            f2bf(o[m][nb][j] * linv[m][j]);
      }
}

extern "C" void kernel_launch(void* const* d_in, const int* in_sizes, int n_in,
                              void* d_out, int out_size, void* d_ws, size_t ws_size,
                              hipStream_t stream) {
  const float* x = (const float*)d_in[0];
  const float* cosp = (const float*)d_in[1];
  const float* sinp = (const float*)d_in[2];
  const float* Wq = (const float*)d_in[3];
  const float* Wk = (const float*)d_in[4];
  const float* Wv = (const float*)d_in[5];
  const float* Wo = (const float*)d_in[6];
  float* out = (float*)d_out;

  char* ws = (char*)d_ws;
  size_t off = 0;
  auto alloc = [&](size_t bytes) { void* p = ws + off; off += bytes; return p; };
  const size_t BT = (size_t)B_SZ * T_SEQ;  // 8192
  unsigned short* xb = (unsigned short*)alloc(BT * C_DIM * 2);              // 32MB
  unsigned short* WqkvT = (unsigned short*)alloc((size_t)3072 * 2048 * 2);  // 12.6MB
  unsigned short* WoT = (unsigned short*)alloc((size_t)2048 * 2048 * 2);    // 8.4MB
  unsigned short* qkv = (unsigned short*)alloc(BT * 3072 * 2);              // 48MB
  unsigned short* Kb = (unsigned short*)alloc(BT * 512 * 2);                // 8MB
  unsigned short* Vb = (unsigned short*)alloc(BT * 512 * 2);                // 8MB
  unsigned short* Qb = xb;   // alias: xb dead after qkv GEMM
  unsigned short* Yb = qkv;  // alias: qkv dead after ropeAll/vtrans

  dim3 tb(32, 8);
  cast_x<<<16384, 256, 0, stream>>>(x, xb, (int)(BT * C_DIM / 4));
  wtransAll<<<dim3(64, 160), tb, 0, stream>>>(Wq, Wk, Wv, Wo, WqkvT, WoT);

  // qkv GEMM: M=8192 (64 x 128-tiles), N=3072 (12 x 256-tiles) -> 768 blocks = 3.0 rounds
  gemm128<unsigned short><<<768, 512, 0, stream>>>(xb, WqkvT, qkv, 3072, 2048, 64);

  ropeAll<<<(B_SZ * T_SEQ * 20) / 4, 256, 0, stream>>>(qkv, cosp, sinp, Qb, Kb);
  vtrans<<<dim3(64, 4, 16), tb, 0, stream>>>(qkv, Vb);

  attn<<<dim3(1024), 256, 0, stream>>>(Qb, Kb, Vb, Yb);

  // out-proj GEMM: M=8192, N=2048 -> 32 x 8 = 256 blocks = 1.0 round
  gemm256<float><<<256, 512, 0, stream>>>(Yb, WoT, out, 2048, 2048, 32);
}